// Round 11
// baseline (3059.691 us; speedup 1.0000x reference)
//
#include <hip/hip_runtime.h>
#include <cstddef>
#include <cstdint>

// ---------------------------------------------------------------------------
// AttentionalGNN: 3 x (GAT, self-attn, cross-attn)
// B=8, D=256, NQ=4096, N3=2048, N1=16384, heads=4, dim=64
// Round 11: conv = DIRECT-FROM-GLOBAL register GEMM (no LDS, no barriers).
//   Both operands K-contiguous -> per-lane 16B fragment loads straight from
//   L2/L3-resident buffers; loop-invariant row bases; launch_bounds(256,4)
//   caps VGPR at 128 -> 16 waves/CU.  Rest identical to round 10.
// ---------------------------------------------------------------------------

#define NQ 4096
#define N3C 2048
#define NT 6144
#define N1 16384
#define BATCH 8

typedef __attribute__((ext_vector_type(8))) short bf16x8;
typedef __attribute__((ext_vector_type(4))) float f32x4;

__device__ __forceinline__ unsigned short f2bf(float f) {
    union { float f; unsigned u; } v; v.f = f;
    unsigned r = v.u + 0x7fffu + ((v.u >> 16) & 1u);
    return (unsigned short)(r >> 16);
}
__device__ __forceinline__ float bf2f(unsigned short h) {
    union { unsigned u; float f; } v; v.u = ((unsigned)h) << 16; return v.f;
}
__device__ __forceinline__ unsigned pack2(float lo, float hi) {
    return ((unsigned)f2bf(hi) << 16) | f2bf(lo);
}
// XOR swizzle for 64-bf16-wide (128B) LDS rows (attention tiles)
__device__ __forceinline__ int swz(int row, int byteoff) {
    return row * 128 + (byteoff ^ ((row & 7) << 4));
}

#define OM_BF16T  1
#define OM_BF16N  3
#define OM_ACC2_T 6
#define OM_QKV    7

// ---------------------------------------------------------------------------
// MFMA GEMM: out(o,n) = bias[o] + sum_c W[o][c] * X[n][c]   (per batch b)
// No LDS, no barriers: per-lane 16B fragment loads direct from global
// (W and X are K-contiguous).  Row bases loop-invariant.
// ---------------------------------------------------------------------------
__global__ __launch_bounds__(256, 4) void conv_mfma_kernel(
    const unsigned short* __restrict__ W,
    const unsigned short* __restrict__ XA, int CA,
    const unsigned short* __restrict__ XB,
    int C, int xstride,
    const float* __restrict__ bias,
    float* __restrict__ outF, float* __restrict__ outF2,
    unsigned short* __restrict__ outT,
    unsigned short* __restrict__ outT2,
    int outMode, int O, int ldo, int N)
{
    const int b  = blockIdx.z;
    const int o0 = blockIdx.y * 128;
    const int n0 = blockIdx.x * 128;
    const int tid = threadIdx.x;
    const int wid = tid >> 6, lane = tid & 63;
    const int wr = wid >> 1, wc = wid & 1;
    const int lr = lane & 15, kg = lane >> 4;
    const int CB = C - CA;

    // loop-invariant row base pointers (compiler folds c0 into imm offsets)
    const unsigned short* wp[4];
    const unsigned short* xa[4];
    const unsigned short* xb[4];
    const unsigned short* XBs = XB ? XB : XA;
    const int CBs = CB ? CB : CA;
    #pragma unroll
    for (int m = 0; m < 4; ++m)
        wp[m] = W + (size_t)(o0 + wr * 64 + m * 16 + lr) * C + kg * 8;
    #pragma unroll
    for (int n = 0; n < 4; ++n) {
        int row = n0 + wc * 64 + n * 16 + lr;
        xa[n] = XA  + ((size_t)b * xstride + row) * CA  + kg * 8;
        xb[n] = XBs + ((size_t)b * xstride + row) * CBs + kg * 8;
    }

    f32x4 acc[4][4] = {};

    for (int c0 = 0; c0 < C; c0 += 32) {
        bf16x8 af[4], bfr[4];
        #pragma unroll
        for (int m = 0; m < 4; ++m)
            af[m] = *(const bf16x8*)(wp[m] + c0);
        const bool inA = (c0 < CA);   // c0 mult of 32, CA mult of 32, kg*8<32
        #pragma unroll
        for (int n = 0; n < 4; ++n)
            bfr[n] = inA ? *(const bf16x8*)(xa[n] + c0)
                         : *(const bf16x8*)(xb[n] + (c0 - CA));
        #pragma unroll
        for (int m = 0; m < 4; ++m)
            #pragma unroll
            for (int n = 0; n < 4; ++n)
                acc[m][n] = __builtin_amdgcn_mfma_f32_16x16x32_bf16(
                    af[m], bfr[n], acc[m][n], 0, 0, 0);
    }

    // C/D frag: col = lane&15, row = (lane>>4)*4 + r
    #pragma unroll
    for (int m = 0; m < 4; ++m) {
        const int ob = o0 + wr * 64 + m * 16 + (lane >> 4) * 4;
        float bv[4] = {0.f, 0.f, 0.f, 0.f};
        if (bias) {
            #pragma unroll
            for (int r = 0; r < 4; ++r) bv[r] = bias[ob + r];
        }
        #pragma unroll
        for (int n = 0; n < 4; ++n) {
            const int col = n0 + wc * 64 + n * 16 + lr;
            f32x4 v = acc[m][n];
            #pragma unroll
            for (int r = 0; r < 4; ++r) v[r] += bv[r];
            if (outMode == OM_BF16T) {
                *(uint2*)(outT + ((size_t)b * N + col) * ldo + ob) =
                    make_uint2(pack2(v[0], v[1]), pack2(v[2], v[3]));
            } else if (outMode == OM_QKV) {
                if (ob < 256) {
                    #pragma unroll
                    for (int r = 0; r < 4; ++r) {
                        float x = v[r];
                        v[r] = x > 0.f ? x + 1.0f : __expf(x);
                    }
                    *(uint2*)(outT + ((size_t)b * N + col) * 256 + ob) =
                        make_uint2(pack2(v[0], v[1]), pack2(v[2], v[3]));
                } else {
                    #pragma unroll
                    for (int r = 0; r < 4; ++r) {
                        int ch = ob + r - 256;
                        float x = v[r];
                        if (ch < 256) x = x > 0.f ? x + 1.0f : __expf(x);
                        outT2[((size_t)b * 512 + ch) * N + col] = f2bf(x);
                    }
                }
            } else if (outMode == OM_ACC2_T) {
                #pragma unroll
                for (int r = 0; r < 4; ++r) {
                    float* p;
                    if (col < NQ)
                        p = outF  + ((size_t)b * 256 + ob + r) * NQ  + col;
                    else
                        p = outF2 + ((size_t)b * 256 + ob + r) * N3C + (col - NQ);
                    float nv = *p + v[r];
                    *p = nv;
                    v[r] = nv;
                }
                *(uint2*)(outT + ((size_t)b * N + col) * ldo + ob) =
                    make_uint2(pack2(v[0], v[1]), pack2(v[2], v[3]));
            } else {  // OM_BF16N (weight-build, b==0)
                #pragma unroll
                for (int r = 0; r < 4; ++r)
                    outT[(size_t)(ob + r) * ldo + col] = f2bf(v[r]);
            }
        }
    }
}

// ---------------------------------------------------------------------------
// fp32 [B][C][Ncols] -> bf16 [B][rs][C] at row offset ro
// ---------------------------------------------------------------------------
__global__ __launch_bounds__(256) void tcvt_kernel(
    const float* __restrict__ in, unsigned short* __restrict__ out,
    int C, int Ncols, int rs, int ro)
{
    int b = blockIdx.z;
    int n0 = blockIdx.x * 64, c0 = blockIdx.y * 64;
    __shared__ float t[64][65];
    int a = threadIdx.x & 63, q = threadIdx.x >> 6;
    for (int i = q; i < 64; i += 4)
        t[i][a] = in[((size_t)b * C + c0 + i) * Ncols + n0 + a];
    __syncthreads();
    for (int i = q; i < 64; i += 4)
        out[((size_t)b * rs + ro + n0 + i) * C + c0 + a] = f2bf(t[a][i]);
}

__global__ __launch_bounds__(256) void cvt_bf16_kernel(
    const float* __restrict__ in, unsigned short* __restrict__ out, size_t n)
{
    size_t i = (size_t)blockIdx.x * 256 + threadIdx.x;
    size_t stride = (size_t)gridDim.x * 256;
    for (; i < n; i += stride) out[i] = f2bf(in[i]);
}

// pw [18][256][256] -> bf16, ALL sections row-permuted h-major:
// out_row r <- src_row (r&63)*4 + (r>>6)
__global__ __launch_bounds__(256) void pwperm_cvt_kernel(
    const float* __restrict__ pw, unsigned short* __restrict__ out)
{
    size_t i = (size_t)blockIdx.x * 256 + threadIdx.x;
    size_t stride = (size_t)gridDim.x * 256;
    size_t total = (size_t)18 * 65536;
    for (; i < total; i += stride) {
        int sec = (int)(i >> 16);
        int r = (int)((i >> 8) & 255);
        int c = (int)(i & 255);
        int srow = (r & 63) * 4 + (r >> 6);
        out[i] = f2bf(pw[(size_t)sec * 65536 + (size_t)srow * 256 + c]);
    }
}

// permuted qkv bias (768/ai): all three sections h-major permuted
__global__ __launch_bounds__(256) void pbqkv_perm_kernel(
    const float* __restrict__ pb, float* __restrict__ pbqkv)
{
    int ai = blockIdx.x, sec = blockIdx.y, r = threadIdx.x;
    pbqkv[ai * 768 + sec * 256 + r] =
        pb[ai * 768 + sec * 256 + (r & 63) * 4 + (r >> 6)];
}

// fp32 [Z][D][D] -> bf16 transposed [Z][D][D]
__global__ __launch_bounds__(256) void wtrans_cvt_kernel(
    const float* __restrict__ in, unsigned short* __restrict__ out, int D)
{
    int z = blockIdx.z;
    int i0 = blockIdx.x * 64, j0 = blockIdx.y * 64;
    __shared__ float t[64][65];
    int a = threadIdx.x & 63, q = threadIdx.x >> 6;
    const float* src = in + (size_t)z * D * D;
    unsigned short* dst = out + (size_t)z * D * D;
    for (int i = q; i < 64; i += 4)
        t[i][a] = src[(size_t)(j0 + i) * D + i0 + a];
    __syncthreads();
    for (int i = q; i < 64; i += 4)
        dst[(size_t)(i0 + i) * D + j0 + a] = f2bf(t[a][i]);
}

// wmT with h-major permutation: out[ai][n'][c] = mw[ai][c][(n'&63)*4+(n'>>6)]
__global__ __launch_bounds__(256) void wmt_perm_kernel(
    const float* __restrict__ mw, unsigned short* __restrict__ out)
{
    int ai = blockIdx.y, np = blockIdx.x, c = threadIdx.x;
    int orig = (np & 63) * 4 + (np >> 6);
    out[(size_t)ai * 65536 + (size_t)np * 256 + c] =
        f2bf(mw[(size_t)ai * 65536 + (size_t)c * 256 + orig]);
}

// split m1w: A-half into combined [512][512] cols 0-255; B-half [512][256]
__global__ __launch_bounds__(256) void ext_m1_kernel(
    const float* __restrict__ m1w, unsigned short* __restrict__ m1c,
    unsigned short* __restrict__ w1b)
{
    int ai = blockIdx.y, o = blockIdx.x, c = threadIdx.x;
    const float* src = m1w + (size_t)ai * 262144 + (size_t)o * 512;
    m1c[(size_t)ai * 262144 + (size_t)o * 512 + c] = f2bf(src[c]);
    w1b[(size_t)ai * 131072 + (size_t)o * 256 + c] = f2bf(src[256 + c]);
}

// bfold[ai][o] = m1b[ai][o] + sum_c m1w[ai][o][256+c] * mb[ai][c]
__global__ __launch_bounds__(256) void bias_fold_kernel(
    const float* __restrict__ m1w, const float* __restrict__ m1b,
    const float* __restrict__ mb, float* __restrict__ bf)
{
    int ai = blockIdx.y;
    int o = blockIdx.x * 256 + threadIdx.x;
    const float* wrow = m1w + (size_t)ai * 262144 + (size_t)o * 512 + 256;
    const float* mbp = mb + (size_t)ai * 256;
    float s = m1b[(size_t)ai * 512 + o];
    for (int c = 0; c < 256; ++c) s += wrow[c] * mbp[c];
    bf[(size_t)ai * 512 + o] = s;
}

// ---------------------------------------------------------------------------
// Instance norm on bf16 [B][NT][512], per-segment (rows<4096 seg0, else seg1).
// 64-row chunks: grid (96, B) for stats1/apply -> 768 blocks.
// ---------------------------------------------------------------------------
__global__ __launch_bounds__(256) void in_stats1(
    const unsigned short* __restrict__ x, float* __restrict__ part)
{
    int b = blockIdx.y, ch = blockIdx.x, tid = threadIdx.x;
    float s0 = 0, q0 = 0, s1 = 0, q1 = 0;
    for (int r = 0; r < 64; ++r) {
        size_t base = ((size_t)b * NT + ch * 64 + r) * 512;
        float v0 = bf2f(x[base + tid]);
        float v1 = bf2f(x[base + 256 + tid]);
        s0 += v0; q0 += v0 * v0; s1 += v1; q1 += v1 * v1;
    }
    size_t p = ((size_t)(b * 96 + ch)) * 1024;
    part[p + tid] = s0;  part[p + 256 + tid] = q0;
    part[p + 512 + tid] = s1;  part[p + 768 + tid] = q1;
}

// grid (B, 2): per-seg reduce.  mr[b][seg][1024]
__global__ __launch_bounds__(512) void in_stats2(
    const float* __restrict__ part, float* __restrict__ mr)
{
    int b = blockIdx.x, seg = blockIdx.y, c = threadIdx.x;
    int half = c >> 8, cc = c & 255;
    int ch0 = seg ? 64 : 0, nch = seg ? 32 : 64;
    float Nf = seg ? (float)N3C : (float)NQ;
    float s = 0, q = 0;
    for (int ch = ch0; ch < ch0 + nch; ++ch) {
        size_t p = ((size_t)(b * 96 + ch)) * 1024 + half * 512;
        s += part[p + cc];
        q += part[p + 256 + cc];
    }
    float m = s / Nf;
    float var = q / Nf - m * m;
    size_t o = ((size_t)b * 2 + seg) * 1024;
    mr[o + c] = m;
    mr[o + 512 + c] = rsqrtf(var + 1e-5f);
}

__global__ __launch_bounds__(256) void in_apply(
    unsigned short* __restrict__ x, const float* __restrict__ mr)
{
    int b = blockIdx.y, ch = blockIdx.x, tid = threadIdx.x;
    int seg = (ch >= 64);
    size_t o = ((size_t)b * 2 + seg) * 1024;
    float m0 = mr[o + tid];
    float r0 = mr[o + 512 + tid];
    float m1 = mr[o + 256 + tid];
    float r1 = mr[o + 768 + tid];
    for (int r = 0; r < 64; ++r) {
        size_t base = ((size_t)b * NT + ch * 64 + r) * 512;
        float v0 = (bf2f(x[base + tid]) - m0) * r0;
        x[base + tid] = f2bf(v0 > 0.f ? v0 : 0.f);
        float v1 = (bf2f(x[base + 256 + tid]) - m1) * r1;
        x[base + 256 + tid] = f2bf(v1 > 0.f ? v1 : 0.f);
    }
}

// ---------------------------------------------------------------------------
// KV split partial (MFMA).  KVcm bf16 [B][512][NT] channel-major h-grouped:
// k channel = h*64+d (elu'd), v channel = 256+h*64+q.
// grid (24, 4, 8): sx<16 -> srcseg0 (m 0-4095), else srcseg1 (m 4096-6143).
// dstseg = cross ? 1-srcseg : srcseg.  chunk = 256 m per split (4 x 64 tiles).
// ---------------------------------------------------------------------------
__global__ __launch_bounds__(64) void kv_partial_mfma(
    const unsigned short* __restrict__ kvcm, float* __restrict__ part,
    int cross)
{
    const int sx = blockIdx.x, h = blockIdx.y, b = blockIdx.z;
    const int srcseg = sx >> 4;
    const int slot = sx & 15;
    const int Mb0 = srcseg ? NQ + slot * 256 : slot * 256;
    const int dstseg = cross ? 1 - srcseg : srcseg;
    const int l = threadIdx.x;
    const int lr = l & 15, kg = l >> 4;

    __shared__ unsigned short ke[64 * 64];
    __shared__ unsigned short ve[64 * 64];

    const size_t kbase = ((size_t)b * 512 + h * 64) * NT;
    const size_t vbase = kbase + (size_t)256 * NT;

    f32x4 acc[4][4] = {};
    float ksacc = 0.f;

    for (int t = 0; t < 4; ++t) {
        const int mb = Mb0 + t * 64;
        #pragma unroll
        for (int p = 0; p < 8; ++p) {
            int row = p * 8 + (l >> 3);
            bf16x8 k8 = *(const bf16x8*)(kvcm + kbase + (size_t)row * NT + mb + (l & 7) * 8);
            bf16x8 v8 = *(const bf16x8*)(kvcm + vbase + (size_t)row * NT + mb + (l & 7) * 8);
            *(bf16x8*)((char*)ke + swz(row, (l & 7) * 16)) = k8;
            *(bf16x8*)((char*)ve + swz(row, (l & 7) * 16)) = v8;
        }

        #pragma unroll
        for (int j = 0; j < 8; ++j) {
            bf16x8 kk = *(const bf16x8*)((const char*)ke + swz(l, j * 16));
            #pragma unroll
            for (int e = 0; e < 8; ++e) ksacc += bf2f((unsigned short)kk[e]);
        }

        #pragma unroll
        for (int ks = 0; ks < 2; ++ks) {
            bf16x8 af[4], bfr[4];
            #pragma unroll
            for (int di = 0; di < 4; ++di)
                af[di] = *(const bf16x8*)((const char*)ke + swz(di * 16 + lr, ks * 64 + kg * 16));
            #pragma unroll
            for (int qi = 0; qi < 4; ++qi)
                bfr[qi] = *(const bf16x8*)((const char*)ve + swz(qi * 16 + lr, ks * 64 + kg * 16));
            #pragma unroll
            for (int di = 0; di < 4; ++di)
                #pragma unroll
                for (int qi = 0; qi < 4; ++qi)
                    acc[di][qi] = __builtin_amdgcn_mfma_f32_16x16x32_bf16(
                        af[di], bfr[qi], acc[di][qi], 0, 0, 0);
        }
    }

    float* pb_ = part + ((size_t)((b * 4 + h) * 2 + dstseg) * 16 + slot) * 4160;
    #pragma unroll
    for (int di = 0; di < 4; ++di)
        #pragma unroll
        for (int qi = 0; qi < 4; ++qi)
            #pragma unroll
            for (int r = 0; r < 4; ++r)
                pb_[(di * 16 + kg * 4 + r) * 64 + qi * 16 + lr] = acc[di][qi][r];
    pb_[4096 + l] = ksacc;
}

// reduce partials -> KVq bf16 [bh][seg][q*64+d] (transposed) + ksum fp32.
// grid (16, 2, 32)
__global__ __launch_bounds__(256) void kv_reduce_t(
    const float* __restrict__ part, unsigned short* __restrict__ KVq,
    float* __restrict__ ks, int cntA, int cntB)
{
    const int seg = blockIdx.y, bh = blockIdx.z;
    const int cnt = seg ? cntB : cntA;
    const float* p0 = part + ((size_t)(bh * 2 + seg) * 16) * 4160;
    int idx = blockIdx.x * 256 + threadIdx.x;
    int q = idx >> 6, d = idx & 63;
    float t = 0.f;
    for (int s = 0; s < cnt; ++s) t += p0[(size_t)s * 4160 + d * 64 + q];
    KVq[((size_t)(bh * 2 + seg)) * 4096 + idx] = f2bf(t);
    if (blockIdx.x == 0 && threadIdx.x < 64) {
        float t2 = 0.f;
        for (int s = 0; s < cnt; ++s) t2 += p0[(size_t)s * 4160 + 4096 + threadIdx.x];
        ks[(bh * 2 + seg) * 64 + threadIdx.x] = t2;
    }
}

// ---------------------------------------------------------------------------
// apply (MFMA): qe bf16 [B][NT][256] h-major, KVq [bh][seg][q][d], ks fp32.
// grid (96, 4, 8): seg from m0.
// ---------------------------------------------------------------------------
__global__ __launch_bounds__(64) void attn_apply_mfma(
    const unsigned short* __restrict__ qe,
    const unsigned short* __restrict__ KVq,
    const float* __restrict__ ksum,
    unsigned short* __restrict__ outT)
{
    const int h = blockIdx.y, b = blockIdx.z;
    const int m0 = blockIdx.x * 64;
    const int seg = (m0 >= NQ);
    const int bhs = (b * 4 + h) * 2 + seg;
    const int l = threadIdx.x;
    const int lr = l & 15, kg = l >> 4;

    __shared__ unsigned short kv[64 * 64];
    __shared__ float zl[64];
    __shared__ float kss[64];

    #pragma unroll
    for (int i = 0; i < 8; ++i) {
        int q = i * 8 + (l >> 3);
        bf16x8 v8 = *(const bf16x8*)(KVq + (size_t)bhs * 4096 + q * 64 + (l & 7) * 8);
        *(bf16x8*)((char*)kv + swz(q, (l & 7) * 16)) = v8;
    }
    kss[l] = ksum[bhs * 64 + l];

    const unsigned short* qrow = qe + ((size_t)b * NT + m0 + l) * 256 + h * 64;
    float den = 0.f;
    #pragma unroll
    for (int i = 0; i < 8; ++i) {
        bf16x8 q8 = *(const bf16x8*)(qrow + i * 8);
        #pragma unroll
        for (int j = 0; j < 8; ++j) den += bf2f((unsigned short)q8[j]) * kss[i * 8 + j];
    }
    zl[l] = 1.0f / (den + 1e-6f);

    f32x4 acc[4][4] = {};   // [qi][mi]
    #pragma unroll
    for (int ks = 0; ks < 2; ++ks) {
        bf16x8 af[4], bfr[4];
        #pragma unroll
        for (int qi = 0; qi < 4; ++qi)
            af[qi] = *(const bf16x8*)((const char*)kv + swz(qi * 16 + lr, ks * 64 + kg * 16));
        #pragma unroll
        for (int mi = 0; mi < 4; ++mi)
            bfr[mi] = *(const bf16x8*)(qe + ((size_t)b * NT + m0 + mi * 16 + lr) * 256
                                       + h * 64 + ks * 32 + kg * 8);
        #pragma unroll
        for (int qi = 0; qi < 4; ++qi)
            #pragma unroll
            for (int mi = 0; mi < 4; ++mi)
                acc[qi][mi] = __builtin_amdgcn_mfma_f32_16x16x32_bf16(
                    af[qi], bfr[mi], acc[qi][mi], 0, 0, 0);
    }

    #pragma unroll
    for (int mi = 0; mi < 4; ++mi) {
        int m = m0 + mi * 16 + lr;
        float Z = zl[mi * 16 + lr];
        unsigned short* dst = outT + ((size_t)b * NT + m) * 256 + h * 64;
        #pragma unroll
        for (int qi = 0; qi < 4; ++qi) {
            f32x4 v = acc[qi][mi];
            *(uint2*)(dst + qi * 16 + kg * 4) =
                make_uint2(pack2(v[0] * Z, v[1] * Z), pack2(v[2] * Z, v[3] * Z));
        }
    }
}

// ---------------------------------------------------------------------------
// GAT: wave-per-node; writes fp32 P_D3 and bf16 rows 4096+ of combined TX.
// ---------------------------------------------------------------------------
__global__ __launch_bounds__(256) void gat_fuse_kernel(
    const unsigned short* __restrict__ Wh3T,
    const unsigned short* __restrict__ Wh2T,
    const float* __restrict__ avec,
    float* __restrict__ d3out, unsigned short* __restrict__ tx,
    int n3, int n1)
{
    const int b = blockIdx.y;
    const int n0 = blockIdx.x * 16;
    const int wv = threadIdx.x >> 6, lane = threadIdx.x & 63;
    __shared__ float hbuf[16][256];

    float a1[4], a2[4];
    #pragma unroll
    for (int r = 0; r < 4; ++r) {
        a1[r] = avec[lane + 64 * r];
        a2[r] = avec[256 + lane + 64 * r];
    }

    for (int i = 0; i < 4; ++i) {
        int nl = wv * 4 + i;
        int n = n0 + nl;
        float rows[9][4];
        const unsigned short* p3 = Wh3T + ((size_t)b * n3 + n) * 256;
        #pragma unroll
        for (int r = 0; r < 4; ++r) rows[0][r] = bf2f(p3[lane + 64 * r]);
        #pragma unroll
        for (int l2 = 1; l2 < 9; ++l2) {
            const unsigned short* p2 = Wh2T + ((size_t)b * n1 + (size_t)n * 8 + (l2 - 1)) * 256;
            #pragma unroll
            for (int r = 0; r < 4; ++r) rows[l2][r] = bf2f(p2[lane + 64 * r]);
        }

        float part[10];
        {
            float s = 0.f;
            #pragma unroll
            for (int r = 0; r < 4; ++r) s += rows[0][r] * a1[r];
            part[0] = s;
        }
        #pragma unroll
        for (int l2 = 0; l2 < 9; ++l2) {
            float s = 0.f;
            #pragma unroll
            for (int r = 0; r < 4; ++r) s += rows[l2][r] * a2[r];
            part[1 + l2] = s;
        }
        #pragma unroll
        for (int msk = 1; msk < 64; msk <<= 1)
            #pragma unroll
            for (int j = 0; j < 10; ++j)
                part[j] += __shfl_xor(part[j], msk, 64);

        float s3 = part[0];
        float e[9], mx = -1e30f;
        #pragma unroll
        for (int l2 = 0; l2 < 9; ++l2) {
            float t = s3 + part[1 + l2];
            t = t > 0.f ? t : 0.2f * t;
            e[l2] = t; mx = fmaxf(mx, t);
        }
        float sum = 0.f;
        #pragma unroll
        for (int l2 = 0; l2 < 9; ++l2) { e[l2] = __expf(e[l2] - mx); sum += e[l2]; }
        float inv = 1.0f / sum;
        #pragma unroll
        for (int r = 0; r < 4; ++r) {
            float t = 0.f;
            #pragma unroll
            for (int l2 = 0; l2 < 9; ++l2) t += e[l2] * rows[l2][r];
            t *= inv;
            t = t > 0.f ? t : __expf(t) - 1.0f;  // elu
            hbuf[nl][lane + 64 * r] = t;
            tx[((size_t)b * NT + NQ + n) * 256 + lane + 64 * r] = f2bf(t);
        }
    }
    __syncthreads();
    const int c = threadIdx.x;
    float* dst = d3out + ((size_t)b * 256 + c) * n3 + n0;
    #pragma unroll
    for (int g = 0; g < 4; ++g) {
        f32x4 v;
        #pragma unroll
        for (int k = 0; k < 4; ++k) v[k] = hbuf[g * 4 + k][c];
        *(f32x4*)(dst + g * 4) = v;
    }
}

// ---------------------------------------------------------------------------
// host side
// ---------------------------------------------------------------------------
static void conv_mfma(hipStream_t s, const unsigned short* W,
                      const unsigned short* XA, int CA,
                      const unsigned short* XB, int C, int xstride,
                      const float* bias, float* outF, float* outF2,
                      unsigned short* outT, unsigned short* outT2,
                      int mode, int O, int ldo, int N, int nb)
{
    dim3 g(N / 128, O / 128, nb);
    conv_mfma_kernel<<<g, 256, 0, s>>>(W, XA, CA, XB, C, xstride, bias,
                                       outF, outF2, outT, outT2, mode, O, ldo, N);
}

extern "C" void kernel_launch(void* const* d_in, const int* in_sizes, int n_in,
                              void* d_out, int out_size, void* d_ws, size_t ws_size,
                              hipStream_t stream)
{
    const float* in_q  = (const float*)d_in[0];
    const float* in_d3 = (const float*)d_in[1];
    const float* in_d2 = (const float*)d_in[2];
    const float* gat_W = (const float*)d_in[3];
    const float* gat_a = (const float*)d_in[4];
    const float* pw    = (const float*)d_in[5];
    const float* pb    = (const float*)d_in[6];
    const float* mw    = (const float*)d_in[7];
    const float* mb    = (const float*)d_in[8];
    const float* m1w   = (const float*)d_in[9];
    const float* m1b   = (const float*)d_in[10];
    const float* m2w   = (const float*)d_in[11];
    const float* m2b   = (const float*)d_in[12];

    const size_t SZ_Q  = (size_t)BATCH * 256 * NQ;
    const size_t SZ_D3 = (size_t)BATCH * 256 * N3C;
    const size_t SZ_T  = (size_t)BATCH * NT * 256;    // combined bf16 elems

    float* P_Q  = (float*)d_out;
    float* P_D3 = P_Q + SZ_Q;

    float* w = (float*)d_ws;
    size_t off = 0;
    unsigned short* Qe   = (unsigned short*)(w + off); off += SZ_T / 2;      // 25 MB
    unsigned short* KVcm = (unsigned short*)(w + off); off += SZ_T;          // 50 MB [B][512][NT]
    unsigned short* AttT = (unsigned short*)(w + off); off += SZ_T / 2;
    unsigned short* HbT  = (unsigned short*)(w + off); off += SZ_T;          // [B][NT][512]
    float* kvp = w + off; off += (size_t)32 * 2 * 16 * 4160;                 // 17 MB
    unsigned short* KVq = (unsigned short*)(w + off); off += (size_t)64 * 4096 / 2;
    float* ksb = w + off; off += 64 * 64;
    float* part = w + off; off += (size_t)BATCH * 96 * 1024;
    float* mr   = w + off; off += (size_t)BATCH * 2 * 1024;
    unsigned short* TXa = (unsigned short*)(w + off); off += SZ_T / 2;
    unsigned short* TXb = (unsigned short*)(w + off); off += SZ_T / 2;
    unsigned short* TD2 = (unsigned short*)(w + off); off += (size_t)BATCH * N1 * 256 / 2;
    unsigned short* wb_pw  = (unsigned short*)(w + off); off += (size_t)18 * 65536 / 2;
    unsigned short* wb_gat = (unsigned short*)(w + off); off += (size_t)3 * 65536 / 2;
    unsigned short* wb_wmT = (unsigned short*)(w + off); off += (size_t)6 * 65536 / 2;
    unsigned short* wb_m1c = (unsigned short*)(w + off); off += (size_t)6 * 262144 / 2;
    unsigned short* wb_w1b = (unsigned short*)(w + off); off += (size_t)6 * 131072 / 2;
    unsigned short* wb_m2  = (unsigned short*)(w + off); off += (size_t)6 * 131072 / 2;
    float* bfold = w + off; off += 6 * 512;
    float* pbqkv = w + off; off += 6 * 768;

    // GAT overlays: Wh2T (67 MB) spans Qe+KVcm (75 MB); Wh3T (8.4 MB) in AttT.
    unsigned short* Wh2T = Qe;
    unsigned short* Wh3T = AttT;

    // ---- setup ----
    pwperm_cvt_kernel<<<1024, 256, 0, stream>>>(pw, wb_pw);
    pbqkv_perm_kernel<<<dim3(6, 3), 256, 0, stream>>>(pb, pbqkv);
    wtrans_cvt_kernel<<<dim3(4, 4, 3), 256, 0, stream>>>(gat_W, wb_gat, 256);
    wmt_perm_kernel<<<dim3(256, 6), 256, 0, stream>>>(mw, wb_wmT);
    ext_m1_kernel<<<dim3(512, 6), 256, 0, stream>>>(m1w, wb_m1c, wb_w1b);
    cvt_bf16_kernel<<<1024, 256, 0, stream>>>(m2w, wb_m2, (size_t)6 * 131072);
    bias_fold_kernel<<<dim3(2, 6), 256, 0, stream>>>(m1w, m1b, mb, bfold);
    for (int ai = 0; ai < 6; ++ai)   // Wc = W1b @ Wm (perm cols) -> m1c cols 256+
        conv_mfma(stream, wb_w1b + (size_t)ai * 131072,
                  wb_wmT + (size_t)ai * 65536, 256, nullptr, 256, 256,
                  nullptr, nullptr, nullptr,
                  wb_m1c + (size_t)ai * 262144 + 256, nullptr,
                  OM_BF16N, 512, 512, 256, 1);

    tcvt_kernel<<<dim3(NQ / 64, 4, BATCH), 256, 0, stream>>>(in_q,  TXa, 256, NQ, NT, 0);
    tcvt_kernel<<<dim3(N3C / 64, 4, BATCH), 256, 0, stream>>>(in_d3, TXa, 256, N3C, NT, NQ);
    tcvt_kernel<<<dim3(N1 / 64, 4, BATCH), 256, 0, stream>>>(in_d2, TD2, 256, N1, N1, 0);

    hipMemcpyAsync(P_Q,  in_q,  SZ_Q  * sizeof(float), hipMemcpyDeviceToDevice, stream);
    hipMemcpyAsync(P_D3, in_d3, SZ_D3 * sizeof(float), hipMemcpyDeviceToDevice, stream);

    unsigned short *TX = TXa, *TXn = TXb;

    int gi = 0, ai = 0;
    for (int L = 0; L < 9; ++L) {
        int kind = L % 3;
        if (kind == 0) {
            conv_mfma(stream, wb_gat + (size_t)gi * 65536,
                      TX + (size_t)NQ * 256, 256, nullptr, 256, NT,
                      nullptr, nullptr, nullptr, Wh3T, nullptr,
                      OM_BF16T, 256, 256, N3C, BATCH);
            conv_mfma(stream, wb_gat + (size_t)gi * 65536,
                      TD2, 256, nullptr, 256, N1,
                      nullptr, nullptr, nullptr, Wh2T, nullptr,
                      OM_BF16T, 256, 256, N1, BATCH);
            gat_fuse_kernel<<<dim3(N3C / 16, BATCH), 256, 0, stream>>>(
                Wh3T, Wh2T, gat_a + (size_t)gi * 512, P_D3, TX, N3C, N1);
            gi++;
        } else {
            int cross = (kind == 2) ? 1 : 0;
            const unsigned short* wqkv = wb_pw + (size_t)ai * 3 * 65536;  // [768][256]
            const float* pbqkv_ai = pbqkv + (size_t)ai * 768;
            const unsigned short* wm1c = wb_m1c + (size_t)ai * 262144;
            const float* bfi = bfold + (size_t)ai * 512;
            const unsigned short* wm2 = wb_m2 + (size_t)ai * 131072;
            const float* m2bi = m2b + (size_t)ai * 256;
            const int cntA = cross ? 8 : 16;
            const int cntB = cross ? 16 : 8;

            conv_mfma(stream, wqkv, TX, 256, nullptr, 256, NT, pbqkv_ai,
                      nullptr, nullptr, Qe, KVcm, OM_QKV, 768, 256, NT, BATCH);
            kv_partial_mfma<<<dim3(24, 4, BATCH), 64, 0, stream>>>(KVcm, kvp, cross);
            kv_reduce_t<<<dim3(16, 2, 32), 256, 0, stream>>>(kvp, KVq, ksb, cntA, cntB);
            attn_apply_mfma<<<dim3(NT / 64, 4, BATCH), 64, 0, stream>>>(Qe, KVq, ksb, AttT);
            conv_mfma(stream, wm1c, TX, 256, AttT, 512, NT, bfi,
                      nullptr, nullptr, HbT, nullptr, OM_BF16T, 512, 512, NT, BATCH);
            in_stats1<<<dim3(96, BATCH), 256, 0, stream>>>(HbT, part);
            in_stats2<<<dim3(BATCH, 2), 512, 0, stream>>>(part, mr);
            in_apply<<<dim3(96, BATCH), 256, 0, stream>>>(HbT, mr);
            conv_mfma(stream, wm2, HbT, 512, nullptr, 512, NT, m2bi,
                      P_Q, P_D3, TXn, nullptr, OM_ACC2_T, 256, 256, NT, BATCH);
            unsigned short* t = TX; TX = TXn; TXn = t;
            ai++;
        }
    }
    (void)in_sizes; (void)n_in; (void)out_size; (void)ws_size;
}

// Round 12
// 3049.576 us; speedup vs baseline: 1.0033x; 1.0033x over previous
//
#include <hip/hip_runtime.h>
#include <cstddef>
#include <cstdint>

// ---------------------------------------------------------------------------
// AttentionalGNN: 3 x (GAT, self-attn, cross-attn)
// B=8, D=256, NQ=4096, N3=2048, N1=16384, heads=4, dim=64
// Round 12: round-10 framework + conv tile widened to 128 O x 256 N
//   (4 waves, 32 MFMA/wave/iter, BK=32 double-buffered LDS, 1 barrier/iter).
// ---------------------------------------------------------------------------

#define NQ 4096
#define N3C 2048
#define NT 6144
#define N1 16384
#define BATCH 8

typedef __attribute__((ext_vector_type(8))) short bf16x8;
typedef __attribute__((ext_vector_type(4))) float f32x4;

__device__ __forceinline__ unsigned short f2bf(float f) {
    union { float f; unsigned u; } v; v.f = f;
    unsigned r = v.u + 0x7fffu + ((v.u >> 16) & 1u);
    return (unsigned short)(r >> 16);
}
__device__ __forceinline__ float bf2f(unsigned short h) {
    union { unsigned u; float f; } v; v.u = ((unsigned)h) << 16; return v.f;
}
__device__ __forceinline__ unsigned pack2(float lo, float hi) {
    return ((unsigned)f2bf(hi) << 16) | f2bf(lo);
}
// XOR swizzle for 64-bf16-wide (128B) LDS rows (attention tiles)
__device__ __forceinline__ int swz(int row, int byteoff) {
    return row * 128 + (byteoff ^ ((row & 7) << 4));
}

__device__ __forceinline__ void gload_lds16(const void* g, void* l) {
    __builtin_amdgcn_global_load_lds(
        (const __attribute__((address_space(1))) unsigned int*)g,
        (__attribute__((address_space(3))) unsigned int*)l, 16, 0, 0);
}

#define OM_BF16T  1
#define OM_BF16N  3
#define OM_ACC2_T 6
#define OM_QKV    7

// ---------------------------------------------------------------------------
// MFMA GEMM: out(o,n) = bias[o] + sum_c W[o][c] * X[n][c]   (per batch b)
// 128 O x 256 N block tile, 4 waves (each 64x128 = 4x8 frags, 32 MFMA/iter),
// BK=32 double-buffered LDS, stage-early, one barrier per iter.
// ---------------------------------------------------------------------------
__global__ __launch_bounds__(256) void conv_mfma_kernel(
    const unsigned short* __restrict__ W,
    const unsigned short* __restrict__ XA, int CA,
    const unsigned short* __restrict__ XB,
    int C, int xstride,
    const float* __restrict__ bias,
    float* __restrict__ outF, float* __restrict__ outF2,
    unsigned short* __restrict__ outT,
    unsigned short* __restrict__ outT2,
    int outMode, int O, int ldo, int N)
{
    const int b  = blockIdx.z;
    const int o0 = blockIdx.y * 128;
    const int n0 = blockIdx.x * 256;
    const int tid = threadIdx.x;
    const int wid = tid >> 6, lane = tid & 63;
    const int wr = wid >> 1, wc = wid & 1;
    const int lr = lane & 15, kg = lane >> 4;
    const int CB = C - CA;

    __shared__ short As[2][128 * 32];   // 8 KB each
    __shared__ short Bs[2][256 * 32];   // 16 KB each

    auto stage = [&](int buf, int c0) {
        #pragma unroll
        for (int it = 0; it < 2; ++it) {
            int chunk = it * 256 + tid;
            int row = chunk >> 2;
            int ksw = (chunk & 3) ^ (row & 3);
            gload_lds16(W + (size_t)(o0 + row) * C + c0 + ksw * 8,
                        (char*)As[buf] + it * 4096 + wid * 1024);
        }
        #pragma unroll
        for (int it = 0; it < 4; ++it) {
            int chunk = it * 256 + tid;
            int row = chunk >> 2;
            int ksw = (chunk & 3) ^ (row & 3);
            int cc = c0 + ksw * 8;
            const unsigned short* src =
                (cc < CA) ? XA + ((size_t)b * xstride + n0 + row) * CA + cc
                          : XB + ((size_t)b * xstride + n0 + row) * CB + (cc - CA);
            gload_lds16(src, (char*)Bs[buf] + it * 4096 + wid * 1024);
        }
    };

    f32x4 acc[4][8] = {};

    stage(0, 0);
    __syncthreads();

    int cur = 0;
    for (int c0 = 0; c0 < C; c0 += 32) {
        if (c0 + 32 < C) stage(cur ^ 1, c0 + 32);   // issue next-tile loads first

        const char* Ab = (const char*)As[cur];
        const char* Bb = (const char*)Bs[cur];
        bf16x8 af[4];
        #pragma unroll
        for (int m = 0; m < 4; ++m) {
            int row = wr * 64 + m * 16 + lr;
            af[m] = *(const bf16x8*)(Ab + row * 64 + ((kg ^ (row & 3)) * 16));
        }
        #pragma unroll
        for (int n = 0; n < 8; ++n) {
            int row = wc * 128 + n * 16 + lr;
            bf16x8 bn = *(const bf16x8*)(Bb + row * 64 + ((kg ^ (row & 3)) * 16));
            #pragma unroll
            for (int m = 0; m < 4; ++m)
                acc[m][n] = __builtin_amdgcn_mfma_f32_16x16x32_bf16(
                    af[m], bn, acc[m][n], 0, 0, 0);
        }

        __syncthreads();          // one barrier/iter (drains next-tile loads)
        cur ^= 1;
    }

    // C/D frag: col = lane&15, row = (lane>>4)*4 + r
    #pragma unroll
    for (int m = 0; m < 4; ++m) {
        const int ob = o0 + wr * 64 + m * 16 + (lane >> 4) * 4;
        float bv[4] = {0.f, 0.f, 0.f, 0.f};
        if (bias) {
            #pragma unroll
            for (int r = 0; r < 4; ++r) bv[r] = bias[ob + r];
        }
        #pragma unroll
        for (int n = 0; n < 8; ++n) {
            const int col = n0 + wc * 128 + n * 16 + lr;
            f32x4 v = acc[m][n];
            #pragma unroll
            for (int r = 0; r < 4; ++r) v[r] += bv[r];
            if (outMode == OM_BF16T) {
                *(uint2*)(outT + ((size_t)b * N + col) * ldo + ob) =
                    make_uint2(pack2(v[0], v[1]), pack2(v[2], v[3]));
            } else if (outMode == OM_QKV) {
                if (ob < 256) {
                    #pragma unroll
                    for (int r = 0; r < 4; ++r) {
                        float x = v[r];
                        v[r] = x > 0.f ? x + 1.0f : __expf(x);
                    }
                    *(uint2*)(outT + ((size_t)b * N + col) * 256 + ob) =
                        make_uint2(pack2(v[0], v[1]), pack2(v[2], v[3]));
                } else {
                    #pragma unroll
                    for (int r = 0; r < 4; ++r) {
                        int ch = ob + r - 256;
                        float x = v[r];
                        if (ch < 256) x = x > 0.f ? x + 1.0f : __expf(x);
                        outT2[((size_t)b * 512 + ch) * N + col] = f2bf(x);
                    }
                }
            } else if (outMode == OM_ACC2_T) {
                #pragma unroll
                for (int r = 0; r < 4; ++r) {
                    float* p;
                    if (col < NQ)
                        p = outF  + ((size_t)b * 256 + ob + r) * NQ  + col;
                    else
                        p = outF2 + ((size_t)b * 256 + ob + r) * N3C + (col - NQ);
                    float nv = *p + v[r];
                    *p = nv;
                    v[r] = nv;
                }
                *(uint2*)(outT + ((size_t)b * N + col) * ldo + ob) =
                    make_uint2(pack2(v[0], v[1]), pack2(v[2], v[3]));
            } else {  // OM_BF16N (weight-build, b==0)
                #pragma unroll
                for (int r = 0; r < 4; ++r)
                    outT[(size_t)(ob + r) * ldo + col] = f2bf(v[r]);
            }
        }
    }
}

// ---------------------------------------------------------------------------
// fp32 [B][C][Ncols] -> bf16 [B][rs][C] at row offset ro
// ---------------------------------------------------------------------------
__global__ __launch_bounds__(256) void tcvt_kernel(
    const float* __restrict__ in, unsigned short* __restrict__ out,
    int C, int Ncols, int rs, int ro)
{
    int b = blockIdx.z;
    int n0 = blockIdx.x * 64, c0 = blockIdx.y * 64;
    __shared__ float t[64][65];
    int a = threadIdx.x & 63, q = threadIdx.x >> 6;
    for (int i = q; i < 64; i += 4)
        t[i][a] = in[((size_t)b * C + c0 + i) * Ncols + n0 + a];
    __syncthreads();
    for (int i = q; i < 64; i += 4)
        out[((size_t)b * rs + ro + n0 + i) * C + c0 + a] = f2bf(t[a][i]);
}

__global__ __launch_bounds__(256) void cvt_bf16_kernel(
    const float* __restrict__ in, unsigned short* __restrict__ out, size_t n)
{
    size_t i = (size_t)blockIdx.x * 256 + threadIdx.x;
    size_t stride = (size_t)gridDim.x * 256;
    for (; i < n; i += stride) out[i] = f2bf(in[i]);
}

// pw [18][256][256] -> bf16, ALL sections row-permuted h-major:
// out_row r <- src_row (r&63)*4 + (r>>6)
__global__ __launch_bounds__(256) void pwperm_cvt_kernel(
    const float* __restrict__ pw, unsigned short* __restrict__ out)
{
    size_t i = (size_t)blockIdx.x * 256 + threadIdx.x;
    size_t stride = (size_t)gridDim.x * 256;
    size_t total = (size_t)18 * 65536;
    for (; i < total; i += stride) {
        int sec = (int)(i >> 16);
        int r = (int)((i >> 8) & 255);
        int c = (int)(i & 255);
        int srow = (r & 63) * 4 + (r >> 6);
        out[i] = f2bf(pw[(size_t)sec * 65536 + (size_t)srow * 256 + c]);
    }
}

// permuted qkv bias (768/ai): all three sections h-major permuted
__global__ __launch_bounds__(256) void pbqkv_perm_kernel(
    const float* __restrict__ pb, float* __restrict__ pbqkv)
{
    int ai = blockIdx.x, sec = blockIdx.y, r = threadIdx.x;
    pbqkv[ai * 768 + sec * 256 + r] =
        pb[ai * 768 + sec * 256 + (r & 63) * 4 + (r >> 6)];
}

// fp32 [Z][D][D] -> bf16 transposed [Z][D][D]
__global__ __launch_bounds__(256) void wtrans_cvt_kernel(
    const float* __restrict__ in, unsigned short* __restrict__ out, int D)
{
    int z = blockIdx.z;
    int i0 = blockIdx.x * 64, j0 = blockIdx.y * 64;
    __shared__ float t[64][65];
    int a = threadIdx.x & 63, q = threadIdx.x >> 6;
    const float* src = in + (size_t)z * D * D;
    unsigned short* dst = out + (size_t)z * D * D;
    for (int i = q; i < 64; i += 4)
        t[i][a] = src[(size_t)(j0 + i) * D + i0 + a];
    __syncthreads();
    for (int i = q; i < 64; i += 4)
        dst[(size_t)(i0 + i) * D + j0 + a] = f2bf(t[a][i]);
}

// wmT with h-major permutation: out[ai][n'][c] = mw[ai][c][(n'&63)*4+(n'>>6)]
__global__ __launch_bounds__(256) void wmt_perm_kernel(
    const float* __restrict__ mw, unsigned short* __restrict__ out)
{
    int ai = blockIdx.y, np = blockIdx.x, c = threadIdx.x;
    int orig = (np & 63) * 4 + (np >> 6);
    out[(size_t)ai * 65536 + (size_t)np * 256 + c] =
        f2bf(mw[(size_t)ai * 65536 + (size_t)c * 256 + orig]);
}

// split m1w: A-half into combined [512][512] cols 0-255; B-half [512][256]
__global__ __launch_bounds__(256) void ext_m1_kernel(
    const float* __restrict__ m1w, unsigned short* __restrict__ m1c,
    unsigned short* __restrict__ w1b)
{
    int ai = blockIdx.y, o = blockIdx.x, c = threadIdx.x;
    const float* src = m1w + (size_t)ai * 262144 + (size_t)o * 512;
    m1c[(size_t)ai * 262144 + (size_t)o * 512 + c] = f2bf(src[c]);
    w1b[(size_t)ai * 131072 + (size_t)o * 256 + c] = f2bf(src[256 + c]);
}

// bfold[ai][o] = m1b[ai][o] + sum_c m1w[ai][o][256+c] * mb[ai][c]
__global__ __launch_bounds__(256) void bias_fold_kernel(
    const float* __restrict__ m1w, const float* __restrict__ m1b,
    const float* __restrict__ mb, float* __restrict__ bf)
{
    int ai = blockIdx.y;
    int o = blockIdx.x * 256 + threadIdx.x;
    const float* wrow = m1w + (size_t)ai * 262144 + (size_t)o * 512 + 256;
    const float* mbp = mb + (size_t)ai * 256;
    float s = m1b[(size_t)ai * 512 + o];
    for (int c = 0; c < 256; ++c) s += wrow[c] * mbp[c];
    bf[(size_t)ai * 512 + o] = s;
}

// ---------------------------------------------------------------------------
// Instance norm on bf16 [B][NT][512], per-segment (rows<4096 seg0, else seg1).
// 64-row chunks: grid (96, B) for stats1/apply -> 768 blocks.
// ---------------------------------------------------------------------------
__global__ __launch_bounds__(256) void in_stats1(
    const unsigned short* __restrict__ x, float* __restrict__ part)
{
    int b = blockIdx.y, ch = blockIdx.x, tid = threadIdx.x;
    float s0 = 0, q0 = 0, s1 = 0, q1 = 0;
    for (int r = 0; r < 64; ++r) {
        size_t base = ((size_t)b * NT + ch * 64 + r) * 512;
        float v0 = bf2f(x[base + tid]);
        float v1 = bf2f(x[base + 256 + tid]);
        s0 += v0; q0 += v0 * v0; s1 += v1; q1 += v1 * v1;
    }
    size_t p = ((size_t)(b * 96 + ch)) * 1024;
    part[p + tid] = s0;  part[p + 256 + tid] = q0;
    part[p + 512 + tid] = s1;  part[p + 768 + tid] = q1;
}

// grid (B, 2): per-seg reduce.  mr[b][seg][1024]
__global__ __launch_bounds__(512) void in_stats2(
    const float* __restrict__ part, float* __restrict__ mr)
{
    int b = blockIdx.x, seg = blockIdx.y, c = threadIdx.x;
    int half = c >> 8, cc = c & 255;
    int ch0 = seg ? 64 : 0, nch = seg ? 32 : 64;
    float Nf = seg ? (float)N3C : (float)NQ;
    float s = 0, q = 0;
    for (int ch = ch0; ch < ch0 + nch; ++ch) {
        size_t p = ((size_t)(b * 96 + ch)) * 1024 + half * 512;
        s += part[p + cc];
        q += part[p + 256 + cc];
    }
    float m = s / Nf;
    float var = q / Nf - m * m;
    size_t o = ((size_t)b * 2 + seg) * 1024;
    mr[o + c] = m;
    mr[o + 512 + c] = rsqrtf(var + 1e-5f);
}

__global__ __launch_bounds__(256) void in_apply(
    unsigned short* __restrict__ x, const float* __restrict__ mr)
{
    int b = blockIdx.y, ch = blockIdx.x, tid = threadIdx.x;
    int seg = (ch >= 64);
    size_t o = ((size_t)b * 2 + seg) * 1024;
    float m0 = mr[o + tid];
    float r0 = mr[o + 512 + tid];
    float m1 = mr[o + 256 + tid];
    float r1 = mr[o + 768 + tid];
    for (int r = 0; r < 64; ++r) {
        size_t base = ((size_t)b * NT + ch * 64 + r) * 512;
        float v0 = (bf2f(x[base + tid]) - m0) * r0;
        x[base + tid] = f2bf(v0 > 0.f ? v0 : 0.f);
        float v1 = (bf2f(x[base + 256 + tid]) - m1) * r1;
        x[base + 256 + tid] = f2bf(v1 > 0.f ? v1 : 0.f);
    }
}

// ---------------------------------------------------------------------------
// KV split partial (MFMA).  KVcm bf16 [B][512][NT] channel-major h-grouped:
// k channel = h*64+d (elu'd), v channel = 256+h*64+q.
// grid (24, 4, 8): sx<16 -> srcseg0 (m 0-4095), else srcseg1 (m 4096-6143).
// dstseg = cross ? 1-srcseg : srcseg.  chunk = 256 m per split (4 x 64 tiles).
// ---------------------------------------------------------------------------
__global__ __launch_bounds__(64) void kv_partial_mfma(
    const unsigned short* __restrict__ kvcm, float* __restrict__ part,
    int cross)
{
    const int sx = blockIdx.x, h = blockIdx.y, b = blockIdx.z;
    const int srcseg = sx >> 4;
    const int slot = sx & 15;
    const int Mb0 = srcseg ? NQ + slot * 256 : slot * 256;
    const int dstseg = cross ? 1 - srcseg : srcseg;
    const int l = threadIdx.x;
    const int lr = l & 15, kg = l >> 4;

    __shared__ unsigned short ke[64 * 64];
    __shared__ unsigned short ve[64 * 64];

    const size_t kbase = ((size_t)b * 512 + h * 64) * NT;
    const size_t vbase = kbase + (size_t)256 * NT;

    f32x4 acc[4][4] = {};
    float ksacc = 0.f;

    for (int t = 0; t < 4; ++t) {
        const int mb = Mb0 + t * 64;
        #pragma unroll
        for (int p = 0; p < 8; ++p) {
            int row = p * 8 + (l >> 3);
            bf16x8 k8 = *(const bf16x8*)(kvcm + kbase + (size_t)row * NT + mb + (l & 7) * 8);
            bf16x8 v8 = *(const bf16x8*)(kvcm + vbase + (size_t)row * NT + mb + (l & 7) * 8);
            *(bf16x8*)((char*)ke + swz(row, (l & 7) * 16)) = k8;
            *(bf16x8*)((char*)ve + swz(row, (l & 7) * 16)) = v8;
        }

        #pragma unroll
        for (int j = 0; j < 8; ++j) {
            bf16x8 kk = *(const bf16x8*)((const char*)ke + swz(l, j * 16));
            #pragma unroll
            for (int e = 0; e < 8; ++e) ksacc += bf2f((unsigned short)kk[e]);
        }

        #pragma unroll
        for (int ks = 0; ks < 2; ++ks) {
            bf16x8 af[4], bfr[4];
            #pragma unroll
            for (int di = 0; di < 4; ++di)
                af[di] = *(const bf16x8*)((const char*)ke + swz(di * 16 + lr, ks * 64 + kg * 16));
            #pragma unroll
            for (int qi = 0; qi < 4; ++qi)
                bfr[qi] = *(const bf16x8*)((const char*)ve + swz(qi * 16 + lr, ks * 64 + kg * 16));
            #pragma unroll
            for (int di = 0; di < 4; ++di)
                #pragma unroll
                for (int qi = 0; qi < 4; ++qi)
                    acc[di][qi] = __builtin_amdgcn_mfma_f32_16x16x32_bf16(
                        af[di], bfr[qi], acc[di][qi], 0, 0, 0);
        }
    }

    float* pb_ = part + ((size_t)((b * 4 + h) * 2 + dstseg) * 16 + slot) * 4160;
    #pragma unroll
    for (int di = 0; di < 4; ++di)
        #pragma unroll
        for (int qi = 0; qi < 4; ++qi)
            #pragma unroll
            for (int r = 0; r < 4; ++r)
                pb_[(di * 16 + kg * 4 + r) * 64 + qi * 16 + lr] = acc[di][qi][r];
    pb_[4096 + l] = ksacc;
}

// reduce partials -> KVq bf16 [bh][seg][q*64+d] (transposed) + ksum fp32.
// grid (16, 2, 32)
__global__ __launch_bounds__(256) void kv_reduce_t(
    const float* __restrict__ part, unsigned short* __restrict__ KVq,
    float* __restrict__ ks, int cntA, int cntB)
{
    const int seg = blockIdx.y, bh = blockIdx.z;
    const int cnt = seg ? cntB : cntA;
    const float* p0 = part + ((size_t)(bh * 2 + seg) * 16) * 4160;
    int idx = blockIdx.x * 256 + threadIdx.x;
    int q = idx >> 6, d = idx & 63;
    float t = 0.f;
    for (int s = 0; s < cnt; ++s) t += p0[(size_t)s * 4160 + d * 64 + q];
    KVq[((size_t)(bh * 2 + seg)) * 4096 + idx] = f2bf(t);
    if (blockIdx.x == 0 && threadIdx.x < 64) {
        float t2 = 0.f;
        for (int s = 0; s < cnt; ++s) t2 += p0[(size_t)s * 4160 + 4096 + threadIdx.x];
        ks[(bh * 2 + seg) * 64 + threadIdx.x] = t2;
    }
}

// ---------------------------------------------------------------------------
// apply (MFMA): qe bf16 [B][NT][256] h-major, KVq [bh][seg][q][d], ks fp32.
// grid (96, 4, 8): seg from m0.
// ---------------------------------------------------------------------------
__global__ __launch_bounds__(64) void attn_apply_mfma(
    const unsigned short* __restrict__ qe,
    const unsigned short* __restrict__ KVq,
    const float* __restrict__ ksum,
    unsigned short* __restrict__ outT)
{
    const int h = blockIdx.y, b = blockIdx.z;
    const int m0 = blockIdx.x * 64;
    const int seg = (m0 >= NQ);
    const int bhs = (b * 4 + h) * 2 + seg;
    const int l = threadIdx.x;
    const int lr = l & 15, kg = l >> 4;

    __shared__ unsigned short kv[64 * 64];
    __shared__ float zl[64];
    __shared__ float kss[64];

    #pragma unroll
    for (int i = 0; i < 8; ++i) {
        int q = i * 8 + (l >> 3);
        bf16x8 v8 = *(const bf16x8*)(KVq + (size_t)bhs * 4096 + q * 64 + (l & 7) * 8);
        *(bf16x8*)((char*)kv + swz(q, (l & 7) * 16)) = v8;
    }
    kss[l] = ksum[bhs * 64 + l];

    const unsigned short* qrow = qe + ((size_t)b * NT + m0 + l) * 256 + h * 64;
    float den = 0.f;
    #pragma unroll
    for (int i = 0; i < 8; ++i) {
        bf16x8 q8 = *(const bf16x8*)(qrow + i * 8);
        #pragma unroll
        for (int j = 0; j < 8; ++j) den += bf2f((unsigned short)q8[j]) * kss[i * 8 + j];
    }
    zl[l] = 1.0f / (den + 1e-6f);

    f32x4 acc[4][4] = {};   // [qi][mi]
    #pragma unroll
    for (int ks = 0; ks < 2; ++ks) {
        bf16x8 af[4], bfr[4];
        #pragma unroll
        for (int qi = 0; qi < 4; ++qi)
            af[qi] = *(const bf16x8*)((const char*)kv + swz(qi * 16 + lr, ks * 64 + kg * 16));
        #pragma unroll
        for (int mi = 0; mi < 4; ++mi)
            bfr[mi] = *(const bf16x8*)(qe + ((size_t)b * NT + m0 + mi * 16 + lr) * 256
                                       + h * 64 + ks * 32 + kg * 8);
        #pragma unroll
        for (int qi = 0; qi < 4; ++qi)
            #pragma unroll
            for (int mi = 0; mi < 4; ++mi)
                acc[qi][mi] = __builtin_amdgcn_mfma_f32_16x16x32_bf16(
                    af[qi], bfr[mi], acc[qi][mi], 0, 0, 0);
    }

    #pragma unroll
    for (int mi = 0; mi < 4; ++mi) {
        int m = m0 + mi * 16 + lr;
        float Z = zl[mi * 16 + lr];
        unsigned short* dst = outT + ((size_t)b * NT + m) * 256 + h * 64;
        #pragma unroll
        for (int qi = 0; qi < 4; ++qi) {
            f32x4 v = acc[qi][mi];
            *(uint2*)(dst + qi * 16 + kg * 4) =
                make_uint2(pack2(v[0] * Z, v[1] * Z), pack2(v[2] * Z, v[3] * Z));
        }
    }
}

// ---------------------------------------------------------------------------
// GAT: wave-per-node; writes fp32 P_D3 and bf16 rows 4096+ of combined TX.
// ---------------------------------------------------------------------------
__global__ __launch_bounds__(256) void gat_fuse_kernel(
    const unsigned short* __restrict__ Wh3T,
    const unsigned short* __restrict__ Wh2T,
    const float* __restrict__ avec,
    float* __restrict__ d3out, unsigned short* __restrict__ tx,
    int n3, int n1)
{
    const int b = blockIdx.y;
    const int n0 = blockIdx.x * 16;
    const int wv = threadIdx.x >> 6, lane = threadIdx.x & 63;
    __shared__ float hbuf[16][256];

    float a1[4], a2[4];
    #pragma unroll
    for (int r = 0; r < 4; ++r) {
        a1[r] = avec[lane + 64 * r];
        a2[r] = avec[256 + lane + 64 * r];
    }

    for (int i = 0; i < 4; ++i) {
        int nl = wv * 4 + i;
        int n = n0 + nl;
        float rows[9][4];
        const unsigned short* p3 = Wh3T + ((size_t)b * n3 + n) * 256;
        #pragma unroll
        for (int r = 0; r < 4; ++r) rows[0][r] = bf2f(p3[lane + 64 * r]);
        #pragma unroll
        for (int l2 = 1; l2 < 9; ++l2) {
            const unsigned short* p2 = Wh2T + ((size_t)b * n1 + (size_t)n * 8 + (l2 - 1)) * 256;
            #pragma unroll
            for (int r = 0; r < 4; ++r) rows[l2][r] = bf2f(p2[lane + 64 * r]);
        }

        float part[10];
        {
            float s = 0.f;
            #pragma unroll
            for (int r = 0; r < 4; ++r) s += rows[0][r] * a1[r];
            part[0] = s;
        }
        #pragma unroll
        for (int l2 = 0; l2 < 9; ++l2) {
            float s = 0.f;
            #pragma unroll
            for (int r = 0; r < 4; ++r) s += rows[l2][r] * a2[r];
            part[1 + l2] = s;
        }
        #pragma unroll
        for (int msk = 1; msk < 64; msk <<= 1)
            #pragma unroll
            for (int j = 0; j < 10; ++j)
                part[j] += __shfl_xor(part[j], msk, 64);

        float s3 = part[0];
        float e[9], mx = -1e30f;
        #pragma unroll
        for (int l2 = 0; l2 < 9; ++l2) {
            float t = s3 + part[1 + l2];
            t = t > 0.f ? t : 0.2f * t;
            e[l2] = t; mx = fmaxf(mx, t);
        }
        float sum = 0.f;
        #pragma unroll
        for (int l2 = 0; l2 < 9; ++l2) { e[l2] = __expf(e[l2] - mx); sum += e[l2]; }
        float inv = 1.0f / sum;
        #pragma unroll
        for (int r = 0; r < 4; ++r) {
            float t = 0.f;
            #pragma unroll
            for (int l2 = 0; l2 < 9; ++l2) t += e[l2] * rows[l2][r];
            t *= inv;
            t = t > 0.f ? t : __expf(t) - 1.0f;  // elu
            hbuf[nl][lane + 64 * r] = t;
            tx[((size_t)b * NT + NQ + n) * 256 + lane + 64 * r] = f2bf(t);
        }
    }
    __syncthreads();
    const int c = threadIdx.x;
    float* dst = d3out + ((size_t)b * 256 + c) * n3 + n0;
    #pragma unroll
    for (int g = 0; g < 4; ++g) {
        f32x4 v;
        #pragma unroll
        for (int k = 0; k < 4; ++k) v[k] = hbuf[g * 4 + k][c];
        *(f32x4*)(dst + g * 4) = v;
    }
}

// ---------------------------------------------------------------------------
// host side
// ---------------------------------------------------------------------------
static void conv_mfma(hipStream_t s, const unsigned short* W,
                      const unsigned short* XA, int CA,
                      const unsigned short* XB, int C, int xstride,
                      const float* bias, float* outF, float* outF2,
                      unsigned short* outT, unsigned short* outT2,
                      int mode, int O, int ldo, int N, int nb)
{
    dim3 g(N / 256, O / 128, nb);
    conv_mfma_kernel<<<g, 256, 0, s>>>(W, XA, CA, XB, C, xstride, bias,
                                       outF, outF2, outT, outT2, mode, O, ldo, N);
}

extern "C" void kernel_launch(void* const* d_in, const int* in_sizes, int n_in,
                              void* d_out, int out_size, void* d_ws, size_t ws_size,
                              hipStream_t stream)
{
    const float* in_q  = (const float*)d_in[0];
    const float* in_d3 = (const float*)d_in[1];
    const float* in_d2 = (const float*)d_in[2];
    const float* gat_W = (const float*)d_in[3];
    const float* gat_a = (const float*)d_in[4];
    const float* pw    = (const float*)d_in[5];
    const float* pb    = (const float*)d_in[6];
    const float* mw    = (const float*)d_in[7];
    const float* mb    = (const float*)d_in[8];
    const float* m1w   = (const float*)d_in[9];
    const float* m1b   = (const float*)d_in[10];
    const float* m2w   = (const float*)d_in[11];
    const float* m2b   = (const float*)d_in[12];

    const size_t SZ_Q  = (size_t)BATCH * 256 * NQ;
    const size_t SZ_D3 = (size_t)BATCH * 256 * N3C;
    const size_t SZ_T  = (size_t)BATCH * NT * 256;    // combined bf16 elems

    float* P_Q  = (float*)d_out;
    float* P_D3 = P_Q + SZ_Q;

    float* w = (float*)d_ws;
    size_t off = 0;
    unsigned short* Qe   = (unsigned short*)(w + off); off += SZ_T / 2;      // 25 MB
    unsigned short* KVcm = (unsigned short*)(w + off); off += SZ_T;          // 50 MB [B][512][NT]
    unsigned short* AttT = (unsigned short*)(w + off); off += SZ_T / 2;
    unsigned short* HbT  = (unsigned short*)(w + off); off += SZ_T;          // [B][NT][512]
    float* kvp = w + off; off += (size_t)32 * 2 * 16 * 4160;                 // 17 MB
    unsigned short* KVq = (unsigned short*)(w + off); off += (size_t)64 * 4096 / 2;
    float* ksb = w + off; off += 64 * 64;
    float* part = w + off; off += (size_t)BATCH * 96 * 1024;
    float* mr   = w + off; off += (size_t)BATCH * 2 * 1024;
    unsigned short* TXa = (unsigned short*)(w + off); off += SZ_T / 2;
    unsigned short* TXb = (unsigned short*)(w + off); off += SZ_T / 2;
    unsigned short* TD2 = (unsigned short*)(w + off); off += (size_t)BATCH * N1 * 256 / 2;
    unsigned short* wb_pw  = (unsigned short*)(w + off); off += (size_t)18 * 65536 / 2;
    unsigned short* wb_gat = (unsigned short*)(w + off); off += (size_t)3 * 65536 / 2;
    unsigned short* wb_wmT = (unsigned short*)(w + off); off += (size_t)6 * 65536 / 2;
    unsigned short* wb_m1c = (unsigned short*)(w + off); off += (size_t)6 * 262144 / 2;
    unsigned short* wb_w1b = (unsigned short*)(w + off); off += (size_t)6 * 131072 / 2;
    unsigned short* wb_m2  = (unsigned short*)(w + off); off += (size_t)6 * 131072 / 2;
    float* bfold = w + off; off += 6 * 512;
    float* pbqkv = w + off; off += 6 * 768;

    // GAT overlays: Wh2T (67 MB) spans Qe+KVcm (75 MB); Wh3T (8.4 MB) in AttT.
    unsigned short* Wh2T = Qe;
    unsigned short* Wh3T = AttT;

    // ---- setup ----
    pwperm_cvt_kernel<<<1024, 256, 0, stream>>>(pw, wb_pw);
    pbqkv_perm_kernel<<<dim3(6, 3), 256, 0, stream>>>(pb, pbqkv);
    wtrans_cvt_kernel<<<dim3(4, 4, 3), 256, 0, stream>>>(gat_W, wb_gat, 256);
    wmt_perm_kernel<<<dim3(256, 6), 256, 0, stream>>>(mw, wb_wmT);
    ext_m1_kernel<<<dim3(512, 6), 256, 0, stream>>>(m1w, wb_m1c, wb_w1b);
    cvt_bf16_kernel<<<1024, 256, 0, stream>>>(m2w, wb_m2, (size_t)6 * 131072);
    bias_fold_kernel<<<dim3(2, 6), 256, 0, stream>>>(m1w, m1b, mb, bfold);
    for (int ai = 0; ai < 6; ++ai)   // Wc = W1b @ Wm (perm cols) -> m1c cols 256+
        conv_mfma(stream, wb_w1b + (size_t)ai * 131072,
                  wb_wmT + (size_t)ai * 65536, 256, nullptr, 256, 256,
                  nullptr, nullptr, nullptr,
                  wb_m1c + (size_t)ai * 262144 + 256, nullptr,
                  OM_BF16N, 512, 512, 256, 1);

    tcvt_kernel<<<dim3(NQ / 64, 4, BATCH), 256, 0, stream>>>(in_q,  TXa, 256, NQ, NT, 0);
    tcvt_kernel<<<dim3(N3C / 64, 4, BATCH), 256, 0, stream>>>(in_d3, TXa, 256, N3C, NT, NQ);
    tcvt_kernel<<<dim3(N1 / 64, 4, BATCH), 256, 0, stream>>>(in_d2, TD2, 256, N1, N1, 0);

    hipMemcpyAsync(P_Q,  in_q,  SZ_Q  * sizeof(float), hipMemcpyDeviceToDevice, stream);
    hipMemcpyAsync(P_D3, in_d3, SZ_D3 * sizeof(float), hipMemcpyDeviceToDevice, stream);

    unsigned short *TX = TXa, *TXn = TXb;

    int gi = 0, ai = 0;
    for (int L = 0; L < 9; ++L) {
        int kind = L % 3;
        if (kind == 0) {
            conv_mfma(stream, wb_gat + (size_t)gi * 65536,
                      TX + (size_t)NQ * 256, 256, nullptr, 256, NT,
                      nullptr, nullptr, nullptr, Wh3T, nullptr,
                      OM_BF16T, 256, 256, N3C, BATCH);
            conv_mfma(stream, wb_gat + (size_t)gi * 65536,
                      TD2, 256, nullptr, 256, N1,
                      nullptr, nullptr, nullptr, Wh2T, nullptr,
                      OM_BF16T, 256, 256, N1, BATCH);
            gat_fuse_kernel<<<dim3(N3C / 16, BATCH), 256, 0, stream>>>(
                Wh3T, Wh2T, gat_a + (size_t)gi * 512, P_D3, TX, N3C, N1);
            gi++;
        } else {
            int cross = (kind == 2) ? 1 : 0;
            const unsigned short* wqkv = wb_pw + (size_t)ai * 3 * 65536;  // [768][256]
            const float* pbqkv_ai = pbqkv + (size_t)ai * 768;
            const unsigned short* wm1c = wb_m1c + (size_t)ai * 262144;
            const float* bfi = bfold + (size_t)ai * 512;
            const unsigned short* wm2 = wb_m2 + (size_t)ai * 131072;
            const float* m2bi = m2b + (size_t)ai * 256;
            const int cntA = cross ? 8 : 16;
            const int cntB = cross ? 16 : 8;

            conv_mfma(stream, wqkv, TX, 256, nullptr, 256, NT, pbqkv_ai,
                      nullptr, nullptr, Qe, KVcm, OM_QKV, 768, 256, NT, BATCH);
            kv_partial_mfma<<<dim3(24, 4, BATCH), 64, 0, stream>>>(KVcm, kvp, cross);
            kv_reduce_t<<<dim3(16, 2, 32), 256, 0, stream>>>(kvp, KVq, ksb, cntA, cntB);
            attn_apply_mfma<<<dim3(NT / 64, 4, BATCH), 64, 0, stream>>>(Qe, KVq, ksb, AttT);
            conv_mfma(stream, wm1c, TX, 256, AttT, 512, NT, bfi,
                      nullptr, nullptr, HbT, nullptr, OM_BF16T, 512, 512, NT, BATCH);
            in_stats1<<<dim3(96, BATCH), 256, 0, stream>>>(HbT, part);
            in_stats2<<<dim3(BATCH, 2), 512, 0, stream>>>(part, mr);
            in_apply<<<dim3(96, BATCH), 256, 0, stream>>>(HbT, mr);
            conv_mfma(stream, wm2, HbT, 512, nullptr, 512, NT, m2bi,
                      P_Q, P_D3, TXn, nullptr, OM_ACC2_T, 256, 256, NT, BATCH);
            unsigned short* t = TX; TX = TXn; TXn = t;
            ai++;
        }
    }
    (void)in_sizes; (void)n_in; (void)out_size; (void)ws_size;
}

// Round 13
// 2067.264 us; speedup vs baseline: 1.4801x; 1.4752x over previous
//
#include <hip/hip_runtime.h>
#include <cstddef>
#include <cstdint>

// ---------------------------------------------------------------------------
// AttentionalGNN: 3 x (GAT, self-attn, cross-attn)
// B=8, D=256, NQ=4096, N3=2048, N1=16384, heads=4, dim=64
// Round 13: best-known combo = r9 double-buffered conv (BK=32, 128x128,
//   one barrier/iter, 32KB LDS) + r10 framework (IN 64-row regrid, QKV-merged
//   conv, combined-state NT=6144, folded merge-conv, MFMA attention).
// ---------------------------------------------------------------------------

#define NQ 4096
#define N3C 2048
#define NT 6144
#define N1 16384
#define BATCH 8

typedef __attribute__((ext_vector_type(8))) short bf16x8;
typedef __attribute__((ext_vector_type(4))) float f32x4;

__device__ __forceinline__ unsigned short f2bf(float f) {
    union { float f; unsigned u; } v; v.f = f;
    unsigned r = v.u + 0x7fffu + ((v.u >> 16) & 1u);
    return (unsigned short)(r >> 16);
}
__device__ __forceinline__ float bf2f(unsigned short h) {
    union { unsigned u; float f; } v; v.u = ((unsigned)h) << 16; return v.f;
}
__device__ __forceinline__ unsigned pack2(float lo, float hi) {
    return ((unsigned)f2bf(hi) << 16) | f2bf(lo);
}
// XOR swizzle for 64-bf16-wide (128B) LDS rows (attention tiles)
__device__ __forceinline__ int swz(int row, int byteoff) {
    return row * 128 + (byteoff ^ ((row & 7) << 4));
}

__device__ __forceinline__ void gload_lds16(const void* g, void* l) {
    __builtin_amdgcn_global_load_lds(
        (const __attribute__((address_space(1))) unsigned int*)g,
        (__attribute__((address_space(3))) unsigned int*)l, 16, 0, 0);
}

#define OM_BF16T  1
#define OM_BF16N  3
#define OM_ACC2_T 6
#define OM_QKV    7

// ---------------------------------------------------------------------------
// MFMA GEMM: out(o,n) = bias[o] + sum_c W[o][c] * X[n][c]   (per batch b)
// BK=32, double-buffered LDS (2x16KB): stage tile t+1 into buf^1, compute
// tile t from buf, single __syncthreads per iter.
// ---------------------------------------------------------------------------
__global__ __launch_bounds__(256) void conv_mfma_kernel(
    const unsigned short* __restrict__ W,
    const unsigned short* __restrict__ XA, int CA,
    const unsigned short* __restrict__ XB,
    int C, int xstride,
    const float* __restrict__ bias,
    float* __restrict__ outF, float* __restrict__ outF2,
    unsigned short* __restrict__ outT,
    unsigned short* __restrict__ outT2,
    int outMode, int O, int ldo, int N)
{
    const int b  = blockIdx.z;
    const int o0 = blockIdx.y * 128;
    const int n0 = blockIdx.x * 128;
    const int tid = threadIdx.x;
    const int wid = tid >> 6, lane = tid & 63;
    const int wr = wid >> 1, wc = wid & 1;
    const int lr = lane & 15, kg = lane >> 4;
    const int CB = C - CA;

    __shared__ short As[2][128 * 32];   // 8 KB each
    __shared__ short Bs[2][128 * 32];

    auto stage = [&](int buf, int c0) {
        #pragma unroll
        for (int it = 0; it < 2; ++it) {
            int chunk = it * 256 + tid;
            int row = chunk >> 2;
            int ksw = (chunk & 3) ^ (row & 3);
            gload_lds16(W + (size_t)(o0 + row) * C + c0 + ksw * 8,
                        (char*)As[buf] + it * 4096 + wid * 1024);
        }
        #pragma unroll
        for (int it = 0; it < 2; ++it) {
            int chunk = it * 256 + tid;
            int row = chunk >> 2;
            int ksw = (chunk & 3) ^ (row & 3);
            int cc = c0 + ksw * 8;
            const unsigned short* src =
                (cc < CA) ? XA + ((size_t)b * xstride + n0 + row) * CA + cc
                          : XB + ((size_t)b * xstride + n0 + row) * CB + (cc - CA);
            gload_lds16(src, (char*)Bs[buf] + it * 4096 + wid * 1024);
        }
    };

    f32x4 acc[4][4] = {};

    stage(0, 0);
    __syncthreads();              // drain prologue loads

    int cur = 0;
    for (int c0 = 0; c0 < C; c0 += 32) {
        if (c0 + 32 < C) stage(cur ^ 1, c0 + 32);   // issue next-tile loads FIRST

        bf16x8 af[4], bfr[4];
        #pragma unroll
        for (int m = 0; m < 4; ++m) {
            int row = wr * 64 + m * 16 + lr;
            af[m] = *(const bf16x8*)((const char*)As[cur] + row * 64 + ((kg ^ (row & 3)) * 16));
        }
        #pragma unroll
        for (int n = 0; n < 4; ++n) {
            int row = wc * 64 + n * 16 + lr;
            bfr[n] = *(const bf16x8*)((const char*)Bs[cur] + row * 64 + ((kg ^ (row & 3)) * 16));
        }
        #pragma unroll
        for (int m = 0; m < 4; ++m)
            #pragma unroll
            for (int n = 0; n < 4; ++n)
                acc[m][n] = __builtin_amdgcn_mfma_f32_16x16x32_bf16(
                    af[m], bfr[n], acc[m][n], 0, 0, 0);

        __syncthreads();          // one barrier/iter: drains next-tile loads
        cur ^= 1;
    }

    // C/D frag: col = lane&15, row = (lane>>4)*4 + r
    #pragma unroll
    for (int m = 0; m < 4; ++m) {
        const int ob = o0 + wr * 64 + m * 16 + (lane >> 4) * 4;
        float bv[4] = {0.f, 0.f, 0.f, 0.f};
        if (bias) {
            #pragma unroll
            for (int r = 0; r < 4; ++r) bv[r] = bias[ob + r];
        }
        #pragma unroll
        for (int n = 0; n < 4; ++n) {
            const int col = n0 + wc * 64 + n * 16 + lr;
            f32x4 v = acc[m][n];
            #pragma unroll
            for (int r = 0; r < 4; ++r) v[r] += bv[r];
            if (outMode == OM_BF16T) {
                *(uint2*)(outT + ((size_t)b * N + col) * ldo + ob) =
                    make_uint2(pack2(v[0], v[1]), pack2(v[2], v[3]));
            } else if (outMode == OM_QKV) {
                if (ob < 256) {
                    #pragma unroll
                    for (int r = 0; r < 4; ++r) {
                        float x = v[r];
                        v[r] = x > 0.f ? x + 1.0f : __expf(x);
                    }
                    *(uint2*)(outT + ((size_t)b * N + col) * 256 + ob) =
                        make_uint2(pack2(v[0], v[1]), pack2(v[2], v[3]));
                } else {
                    #pragma unroll
                    for (int r = 0; r < 4; ++r) {
                        int ch = ob + r - 256;
                        float x = v[r];
                        if (ch < 256) x = x > 0.f ? x + 1.0f : __expf(x);
                        outT2[((size_t)b * 512 + ch) * N + col] = f2bf(x);
                    }
                }
            } else if (outMode == OM_ACC2_T) {
                #pragma unroll
                for (int r = 0; r < 4; ++r) {
                    float* p;
                    if (col < NQ)
                        p = outF  + ((size_t)b * 256 + ob + r) * NQ  + col;
                    else
                        p = outF2 + ((size_t)b * 256 + ob + r) * N3C + (col - NQ);
                    float nv = *p + v[r];
                    *p = nv;
                    v[r] = nv;
                }
                *(uint2*)(outT + ((size_t)b * N + col) * ldo + ob) =
                    make_uint2(pack2(v[0], v[1]), pack2(v[2], v[3]));
            } else {  // OM_BF16N (weight-build, b==0)
                #pragma unroll
                for (int r = 0; r < 4; ++r)
                    outT[(size_t)(ob + r) * ldo + col] = f2bf(v[r]);
            }
        }
    }
}

// ---------------------------------------------------------------------------
// fp32 [B][C][Ncols] -> bf16 [B][rs][C] at row offset ro
// ---------------------------------------------------------------------------
__global__ __launch_bounds__(256) void tcvt_kernel(
    const float* __restrict__ in, unsigned short* __restrict__ out,
    int C, int Ncols, int rs, int ro)
{
    int b = blockIdx.z;
    int n0 = blockIdx.x * 64, c0 = blockIdx.y * 64;
    __shared__ float t[64][65];
    int a = threadIdx.x & 63, q = threadIdx.x >> 6;
    for (int i = q; i < 64; i += 4)
        t[i][a] = in[((size_t)b * C + c0 + i) * Ncols + n0 + a];
    __syncthreads();
    for (int i = q; i < 64; i += 4)
        out[((size_t)b * rs + ro + n0 + i) * C + c0 + a] = f2bf(t[a][i]);
}

__global__ __launch_bounds__(256) void cvt_bf16_kernel(
    const float* __restrict__ in, unsigned short* __restrict__ out, size_t n)
{
    size_t i = (size_t)blockIdx.x * 256 + threadIdx.x;
    size_t stride = (size_t)gridDim.x * 256;
    for (; i < n; i += stride) out[i] = f2bf(in[i]);
}

// pw [18][256][256] -> bf16, ALL sections row-permuted h-major:
// out_row r <- src_row (r&63)*4 + (r>>6)
__global__ __launch_bounds__(256) void pwperm_cvt_kernel(
    const float* __restrict__ pw, unsigned short* __restrict__ out)
{
    size_t i = (size_t)blockIdx.x * 256 + threadIdx.x;
    size_t stride = (size_t)gridDim.x * 256;
    size_t total = (size_t)18 * 65536;
    for (; i < total; i += stride) {
        int sec = (int)(i >> 16);
        int r = (int)((i >> 8) & 255);
        int c = (int)(i & 255);
        int srow = (r & 63) * 4 + (r >> 6);
        out[i] = f2bf(pw[(size_t)sec * 65536 + (size_t)srow * 256 + c]);
    }
}

// permuted qkv bias (768/ai): all three sections h-major permuted
__global__ __launch_bounds__(256) void pbqkv_perm_kernel(
    const float* __restrict__ pb, float* __restrict__ pbqkv)
{
    int ai = blockIdx.x, sec = blockIdx.y, r = threadIdx.x;
    pbqkv[ai * 768 + sec * 256 + r] =
        pb[ai * 768 + sec * 256 + (r & 63) * 4 + (r >> 6)];
}

// fp32 [Z][D][D] -> bf16 transposed [Z][D][D]
__global__ __launch_bounds__(256) void wtrans_cvt_kernel(
    const float* __restrict__ in, unsigned short* __restrict__ out, int D)
{
    int z = blockIdx.z;
    int i0 = blockIdx.x * 64, j0 = blockIdx.y * 64;
    __shared__ float t[64][65];
    int a = threadIdx.x & 63, q = threadIdx.x >> 6;
    const float* src = in + (size_t)z * D * D;
    unsigned short* dst = out + (size_t)z * D * D;
    for (int i = q; i < 64; i += 4)
        t[i][a] = src[(size_t)(j0 + i) * D + i0 + a];
    __syncthreads();
    for (int i = q; i < 64; i += 4)
        dst[(size_t)(i0 + i) * D + j0 + a] = f2bf(t[a][i]);
}

// wmT with h-major permutation: out[ai][n'][c] = mw[ai][c][(n'&63)*4+(n'>>6)]
__global__ __launch_bounds__(256) void wmt_perm_kernel(
    const float* __restrict__ mw, unsigned short* __restrict__ out)
{
    int ai = blockIdx.y, np = blockIdx.x, c = threadIdx.x;
    int orig = (np & 63) * 4 + (np >> 6);
    out[(size_t)ai * 65536 + (size_t)np * 256 + c] =
        f2bf(mw[(size_t)ai * 65536 + (size_t)c * 256 + orig]);
}

// split m1w: A-half into combined [512][512] cols 0-255; B-half [512][256]
__global__ __launch_bounds__(256) void ext_m1_kernel(
    const float* __restrict__ m1w, unsigned short* __restrict__ m1c,
    unsigned short* __restrict__ w1b)
{
    int ai = blockIdx.y, o = blockIdx.x, c = threadIdx.x;
    const float* src = m1w + (size_t)ai * 262144 + (size_t)o * 512;
    m1c[(size_t)ai * 262144 + (size_t)o * 512 + c] = f2bf(src[c]);
    w1b[(size_t)ai * 131072 + (size_t)o * 256 + c] = f2bf(src[256 + c]);
}

// bfold[ai][o] = m1b[ai][o] + sum_c m1w[ai][o][256+c] * mb[ai][c]
__global__ __launch_bounds__(256) void bias_fold_kernel(
    const float* __restrict__ m1w, const float* __restrict__ m1b,
    const float* __restrict__ mb, float* __restrict__ bf)
{
    int ai = blockIdx.y;
    int o = blockIdx.x * 256 + threadIdx.x;
    const float* wrow = m1w + (size_t)ai * 262144 + (size_t)o * 512 + 256;
    const float* mbp = mb + (size_t)ai * 256;
    float s = m1b[(size_t)ai * 512 + o];
    for (int c = 0; c < 256; ++c) s += wrow[c] * mbp[c];
    bf[(size_t)ai * 512 + o] = s;
}

// ---------------------------------------------------------------------------
// Instance norm on bf16 [B][NT][512], per-segment (rows<4096 seg0, else seg1).
// 64-row chunks: grid (96, B) for stats1/apply -> 768 blocks.
// ---------------------------------------------------------------------------
__global__ __launch_bounds__(256) void in_stats1(
    const unsigned short* __restrict__ x, float* __restrict__ part)
{
    int b = blockIdx.y, ch = blockIdx.x, tid = threadIdx.x;
    float s0 = 0, q0 = 0, s1 = 0, q1 = 0;
    for (int r = 0; r < 64; ++r) {
        size_t base = ((size_t)b * NT + ch * 64 + r) * 512;
        float v0 = bf2f(x[base + tid]);
        float v1 = bf2f(x[base + 256 + tid]);
        s0 += v0; q0 += v0 * v0; s1 += v1; q1 += v1 * v1;
    }
    size_t p = ((size_t)(b * 96 + ch)) * 1024;
    part[p + tid] = s0;  part[p + 256 + tid] = q0;
    part[p + 512 + tid] = s1;  part[p + 768 + tid] = q1;
}

// grid (B, 2): per-seg reduce.  mr[b][seg][1024]
__global__ __launch_bounds__(512) void in_stats2(
    const float* __restrict__ part, float* __restrict__ mr)
{
    int b = blockIdx.x, seg = blockIdx.y, c = threadIdx.x;
    int half = c >> 8, cc = c & 255;
    int ch0 = seg ? 64 : 0, nch = seg ? 32 : 64;
    float Nf = seg ? (float)N3C : (float)NQ;
    float s = 0, q = 0;
    for (int ch = ch0; ch < ch0 + nch; ++ch) {
        size_t p = ((size_t)(b * 96 + ch)) * 1024 + half * 512;
        s += part[p + cc];
        q += part[p + 256 + cc];
    }
    float m = s / Nf;
    float var = q / Nf - m * m;
    size_t o = ((size_t)b * 2 + seg) * 1024;
    mr[o + c] = m;
    mr[o + 512 + c] = rsqrtf(var + 1e-5f);
}

__global__ __launch_bounds__(256) void in_apply(
    unsigned short* __restrict__ x, const float* __restrict__ mr)
{
    int b = blockIdx.y, ch = blockIdx.x, tid = threadIdx.x;
    int seg = (ch >= 64);
    size_t o = ((size_t)b * 2 + seg) * 1024;
    float m0 = mr[o + tid];
    float r0 = mr[o + 512 + tid];
    float m1 = mr[o + 256 + tid];
    float r1 = mr[o + 768 + tid];
    for (int r = 0; r < 64; ++r) {
        size_t base = ((size_t)b * NT + ch * 64 + r) * 512;
        float v0 = (bf2f(x[base + tid]) - m0) * r0;
        x[base + tid] = f2bf(v0 > 0.f ? v0 : 0.f);
        float v1 = (bf2f(x[base + 256 + tid]) - m1) * r1;
        x[base + 256 + tid] = f2bf(v1 > 0.f ? v1 : 0.f);
    }
}

// ---------------------------------------------------------------------------
// KV split partial (MFMA).  KVcm bf16 [B][512][NT] channel-major h-grouped:
// k channel = h*64+d (elu'd), v channel = 256+h*64+q.
// grid (24, 4, 8): sx<16 -> srcseg0 (m 0-4095), else srcseg1 (m 4096-6143).
// dstseg = cross ? 1-srcseg : srcseg.  chunk = 256 m per split (4 x 64 tiles).
// ---------------------------------------------------------------------------
__global__ __launch_bounds__(64) void kv_partial_mfma(
    const unsigned short* __restrict__ kvcm, float* __restrict__ part,
    int cross)
{
    const int sx = blockIdx.x, h = blockIdx.y, b = blockIdx.z;
    const int srcseg = sx >> 4;
    const int slot = sx & 15;
    const int Mb0 = srcseg ? NQ + slot * 256 : slot * 256;
    const int dstseg = cross ? 1 - srcseg : srcseg;
    const int l = threadIdx.x;
    const int lr = l & 15, kg = l >> 4;

    __shared__ unsigned short ke[64 * 64];
    __shared__ unsigned short ve[64 * 64];

    const size_t kbase = ((size_t)b * 512 + h * 64) * NT;
    const size_t vbase = kbase + (size_t)256 * NT;

    f32x4 acc[4][4] = {};
    float ksacc = 0.f;

    for (int t = 0; t < 4; ++t) {
        const int mb = Mb0 + t * 64;
        #pragma unroll
        for (int p = 0; p < 8; ++p) {
            int row = p * 8 + (l >> 3);
            bf16x8 k8 = *(const bf16x8*)(kvcm + kbase + (size_t)row * NT + mb + (l & 7) * 8);
            bf16x8 v8 = *(const bf16x8*)(kvcm + vbase + (size_t)row * NT + mb + (l & 7) * 8);
            *(bf16x8*)((char*)ke + swz(row, (l & 7) * 16)) = k8;
            *(bf16x8*)((char*)ve + swz(row, (l & 7) * 16)) = v8;
        }

        #pragma unroll
        for (int j = 0; j < 8; ++j) {
            bf16x8 kk = *(const bf16x8*)((const char*)ke + swz(l, j * 16));
            #pragma unroll
            for (int e = 0; e < 8; ++e) ksacc += bf2f((unsigned short)kk[e]);
        }

        #pragma unroll
        for (int ks = 0; ks < 2; ++ks) {
            bf16x8 af[4], bfr[4];
            #pragma unroll
            for (int di = 0; di < 4; ++di)
                af[di] = *(const bf16x8*)((const char*)ke + swz(di * 16 + lr, ks * 64 + kg * 16));
            #pragma unroll
            for (int qi = 0; qi < 4; ++qi)
                bfr[qi] = *(const bf16x8*)((const char*)ve + swz(qi * 16 + lr, ks * 64 + kg * 16));
            #pragma unroll
            for (int di = 0; di < 4; ++di)
                #pragma unroll
                for (int qi = 0; qi < 4; ++qi)
                    acc[di][qi] = __builtin_amdgcn_mfma_f32_16x16x32_bf16(
                        af[di], bfr[qi], acc[di][qi], 0, 0, 0);
        }
    }

    float* pb_ = part + ((size_t)((b * 4 + h) * 2 + dstseg) * 16 + slot) * 4160;
    #pragma unroll
    for (int di = 0; di < 4; ++di)
        #pragma unroll
        for (int qi = 0; qi < 4; ++qi)
            #pragma unroll
            for (int r = 0; r < 4; ++r)
                pb_[(di * 16 + kg * 4 + r) * 64 + qi * 16 + lr] = acc[di][qi][r];
    pb_[4096 + l] = ksacc;
}

// reduce partials -> KVq bf16 [bh][seg][q*64+d] (transposed) + ksum fp32.
// grid (16, 2, 32)
__global__ __launch_bounds__(256) void kv_reduce_t(
    const float* __restrict__ part, unsigned short* __restrict__ KVq,
    float* __restrict__ ks, int cntA, int cntB)
{
    const int seg = blockIdx.y, bh = blockIdx.z;
    const int cnt = seg ? cntB : cntA;
    const float* p0 = part + ((size_t)(bh * 2 + seg) * 16) * 4160;
    int idx = blockIdx.x * 256 + threadIdx.x;
    int q = idx >> 6, d = idx & 63;
    float t = 0.f;
    for (int s = 0; s < cnt; ++s) t += p0[(size_t)s * 4160 + d * 64 + q];
    KVq[((size_t)(bh * 2 + seg)) * 4096 + idx] = f2bf(t);
    if (blockIdx.x == 0 && threadIdx.x < 64) {
        float t2 = 0.f;
        for (int s = 0; s < cnt; ++s) t2 += p0[(size_t)s * 4160 + 4096 + threadIdx.x];
        ks[(bh * 2 + seg) * 64 + threadIdx.x] = t2;
    }
}

// ---------------------------------------------------------------------------
// apply (MFMA): qe bf16 [B][NT][256] h-major, KVq [bh][seg][q][d], ks fp32.
// grid (96, 4, 8): seg from m0.
// ---------------------------------------------------------------------------
__global__ __launch_bounds__(64) void attn_apply_mfma(
    const unsigned short* __restrict__ qe,
    const unsigned short* __restrict__ KVq,
    const float* __restrict__ ksum,
    unsigned short* __restrict__ outT)
{
    const int h = blockIdx.y, b = blockIdx.z;
    const int m0 = blockIdx.x * 64;
    const int seg = (m0 >= NQ);
    const int bhs = (b * 4 + h) * 2 + seg;
    const int l = threadIdx.x;
    const int lr = l & 15, kg = l >> 4;

    __shared__ unsigned short kv[64 * 64];
    __shared__ float zl[64];
    __shared__ float kss[64];

    #pragma unroll
    for (int i = 0; i < 8; ++i) {
        int q = i * 8 + (l >> 3);
        bf16x8 v8 = *(const bf16x8*)(KVq + (size_t)bhs * 4096 + q * 64 + (l & 7) * 8);
        *(bf16x8*)((char*)kv + swz(q, (l & 7) * 16)) = v8;
    }
    kss[l] = ksum[bhs * 64 + l];

    const unsigned short* qrow = qe + ((size_t)b * NT + m0 + l) * 256 + h * 64;
    float den = 0.f;
    #pragma unroll
    for (int i = 0; i < 8; ++i) {
        bf16x8 q8 = *(const bf16x8*)(qrow + i * 8);
        #pragma unroll
        for (int j = 0; j < 8; ++j) den += bf2f((unsigned short)q8[j]) * kss[i * 8 + j];
    }
    zl[l] = 1.0f / (den + 1e-6f);

    f32x4 acc[4][4] = {};   // [qi][mi]
    #pragma unroll
    for (int ks = 0; ks < 2; ++ks) {
        bf16x8 af[4], bfr[4];
        #pragma unroll
        for (int qi = 0; qi < 4; ++qi)
            af[qi] = *(const bf16x8*)((const char*)kv + swz(qi * 16 + lr, ks * 64 + kg * 16));
        #pragma unroll
        for (int mi = 0; mi < 4; ++mi)
            bfr[mi] = *(const bf16x8*)(qe + ((size_t)b * NT + m0 + mi * 16 + lr) * 256
                                       + h * 64 + ks * 32 + kg * 8);
        #pragma unroll
        for (int qi = 0; qi < 4; ++qi)
            #pragma unroll
            for (int mi = 0; mi < 4; ++mi)
                acc[qi][mi] = __builtin_amdgcn_mfma_f32_16x16x32_bf16(
                    af[qi], bfr[mi], acc[qi][mi], 0, 0, 0);
    }

    #pragma unroll
    for (int mi = 0; mi < 4; ++mi) {
        int m = m0 + mi * 16 + lr;
        float Z = zl[mi * 16 + lr];
        unsigned short* dst = outT + ((size_t)b * NT + m) * 256 + h * 64;
        #pragma unroll
        for (int qi = 0; qi < 4; ++qi) {
            f32x4 v = acc[qi][mi];
            *(uint2*)(dst + qi * 16 + kg * 4) =
                make_uint2(pack2(v[0] * Z, v[1] * Z), pack2(v[2] * Z, v[3] * Z));
        }
    }
}

// ---------------------------------------------------------------------------
// GAT: wave-per-node; writes fp32 P_D3 and bf16 rows 4096+ of combined TX.
// ---------------------------------------------------------------------------
__global__ __launch_bounds__(256) void gat_fuse_kernel(
    const unsigned short* __restrict__ Wh3T,
    const unsigned short* __restrict__ Wh2T,
    const float* __restrict__ avec,
    float* __restrict__ d3out, unsigned short* __restrict__ tx,
    int n3, int n1)
{
    const int b = blockIdx.y;
    const int n0 = blockIdx.x * 16;
    const int wv = threadIdx.x >> 6, lane = threadIdx.x & 63;
    __shared__ float hbuf[16][256];

    float a1[4], a2[4];
    #pragma unroll
    for (int r = 0; r < 4; ++r) {
        a1[r] = avec[lane + 64 * r];
        a2[r] = avec[256 + lane + 64 * r];
    }

    for (int i = 0; i < 4; ++i) {
        int nl = wv * 4 + i;
        int n = n0 + nl;
        float rows[9][4];
        const unsigned short* p3 = Wh3T + ((size_t)b * n3 + n) * 256;
        #pragma unroll
        for (int r = 0; r < 4; ++r) rows[0][r] = bf2f(p3[lane + 64 * r]);
        #pragma unroll
        for (int l2 = 1; l2 < 9; ++l2) {
            const unsigned short* p2 = Wh2T + ((size_t)b * n1 + (size_t)n * 8 + (l2 - 1)) * 256;
            #pragma unroll
            for (int r = 0; r < 4; ++r) rows[l2][r] = bf2f(p2[lane + 64 * r]);
        }

        float part[10];
        {
            float s = 0.f;
            #pragma unroll
            for (int r = 0; r < 4; ++r) s += rows[0][r] * a1[r];
            part[0] = s;
        }
        #pragma unroll
        for (int l2 = 0; l2 < 9; ++l2) {
            float s = 0.f;
            #pragma unroll
            for (int r = 0; r < 4; ++r) s += rows[l2][r] * a2[r];
            part[1 + l2] = s;
        }
        #pragma unroll
        for (int msk = 1; msk < 64; msk <<= 1)
            #pragma unroll
            for (int j = 0; j < 10; ++j)
                part[j] += __shfl_xor(part[j], msk, 64);

        float s3 = part[0];
        float e[9], mx = -1e30f;
        #pragma unroll
        for (int l2 = 0; l2 < 9; ++l2) {
            float t = s3 + part[1 + l2];
            t = t > 0.f ? t : 0.2f * t;
            e[l2] = t; mx = fmaxf(mx, t);
        }
        float sum = 0.f;
        #pragma unroll
        for (int l2 = 0; l2 < 9; ++l2) { e[l2] = __expf(e[l2] - mx); sum += e[l2]; }
        float inv = 1.0f / sum;
        #pragma unroll
        for (int r = 0; r < 4; ++r) {
            float t = 0.f;
            #pragma unroll
            for (int l2 = 0; l2 < 9; ++l2) t += e[l2] * rows[l2][r];
            t *= inv;
            t = t > 0.f ? t : __expf(t) - 1.0f;  // elu
            hbuf[nl][lane + 64 * r] = t;
            tx[((size_t)b * NT + NQ + n) * 256 + lane + 64 * r] = f2bf(t);
        }
    }
    __syncthreads();
    const int c = threadIdx.x;
    float* dst = d3out + ((size_t)b * 256 + c) * n3 + n0;
    #pragma unroll
    for (int g = 0; g < 4; ++g) {
        f32x4 v;
        #pragma unroll
        for (int k = 0; k < 4; ++k) v[k] = hbuf[g * 4 + k][c];
        *(f32x4*)(dst + g * 4) = v;
    }
}

// ---------------------------------------------------------------------------
// host side
// ---------------------------------------------------------------------------
static void conv_mfma(hipStream_t s, const unsigned short* W,
                      const unsigned short* XA, int CA,
                      const unsigned short* XB, int C, int xstride,
                      const float* bias, float* outF, float* outF2,
                      unsigned short* outT, unsigned short* outT2,
                      int mode, int O, int ldo, int N, int nb)
{
    dim3 g(N / 128, O / 128, nb);
    conv_mfma_kernel<<<g, 256, 0, s>>>(W, XA, CA, XB, C, xstride, bias,
                                       outF, outF2, outT, outT2, mode, O, ldo, N);
}

extern "C" void kernel_launch(void* const* d_in, const int* in_sizes, int n_in,
                              void* d_out, int out_size, void* d_ws, size_t ws_size,
                              hipStream_t stream)
{
    const float* in_q  = (const float*)d_in[0];
    const float* in_d3 = (const float*)d_in[1];
    const float* in_d2 = (const float*)d_in[2];
    const float* gat_W = (const float*)d_in[3];
    const float* gat_a = (const float*)d_in[4];
    const float* pw    = (const float*)d_in[5];
    const float* pb    = (const float*)d_in[6];
    const float* mw    = (const float*)d_in[7];
    const float* mb    = (const float*)d_in[8];
    const float* m1w   = (const float*)d_in[9];
    const float* m1b   = (const float*)d_in[10];
    const float* m2w   = (const float*)d_in[11];
    const float* m2b   = (const float*)d_in[12];

    const size_t SZ_Q  = (size_t)BATCH * 256 * NQ;
    const size_t SZ_D3 = (size_t)BATCH * 256 * N3C;
    const size_t SZ_T  = (size_t)BATCH * NT * 256;    // combined bf16 elems

    float* P_Q  = (float*)d_out;
    float* P_D3 = P_Q + SZ_Q;

    float* w = (float*)d_ws;
    size_t off = 0;
    unsigned short* Qe   = (unsigned short*)(w + off); off += SZ_T / 2;      // 25 MB
    unsigned short* KVcm = (unsigned short*)(w + off); off += SZ_T;          // 50 MB [B][512][NT]
    unsigned short* AttT = (unsigned short*)(w + off); off += SZ_T / 2;
    unsigned short* HbT  = (unsigned short*)(w + off); off += SZ_T;          // [B][NT][512]
    float* kvp = w + off; off += (size_t)32 * 2 * 16 * 4160;                 // 17 MB
    unsigned short* KVq = (unsigned short*)(w + off); off += (size_t)64 * 4096 / 2;
    float* ksb = w + off; off += 64 * 64;
    float* part = w + off; off += (size_t)BATCH * 96 * 1024;
    float* mr   = w + off; off += (size_t)BATCH * 2 * 1024;
    unsigned short* TXa = (unsigned short*)(w + off); off += SZ_T / 2;
    unsigned short* TXb = (unsigned short*)(w + off); off += SZ_T / 2;
    unsigned short* TD2 = (unsigned short*)(w + off); off += (size_t)BATCH * N1 * 256 / 2;
    unsigned short* wb_pw  = (unsigned short*)(w + off); off += (size_t)18 * 65536 / 2;
    unsigned short* wb_gat = (unsigned short*)(w + off); off += (size_t)3 * 65536 / 2;
    unsigned short* wb_wmT = (unsigned short*)(w + off); off += (size_t)6 * 65536 / 2;
    unsigned short* wb_m1c = (unsigned short*)(w + off); off += (size_t)6 * 262144 / 2;
    unsigned short* wb_w1b = (unsigned short*)(w + off); off += (size_t)6 * 131072 / 2;
    unsigned short* wb_m2  = (unsigned short*)(w + off); off += (size_t)6 * 131072 / 2;
    float* bfold = w + off; off += 6 * 512;
    float* pbqkv = w + off; off += 6 * 768;

    // GAT overlays: Wh2T (67 MB) spans Qe+KVcm (75 MB); Wh3T (8.4 MB) in AttT.
    unsigned short* Wh2T = Qe;
    unsigned short* Wh3T = AttT;

    // ---- setup ----
    pwperm_cvt_kernel<<<1024, 256, 0, stream>>>(pw, wb_pw);
    pbqkv_perm_kernel<<<dim3(6, 3), 256, 0, stream>>>(pb, pbqkv);
    wtrans_cvt_kernel<<<dim3(4, 4, 3), 256, 0, stream>>>(gat_W, wb_gat, 256);
    wmt_perm_kernel<<<dim3(256, 6), 256, 0, stream>>>(mw, wb_wmT);
    ext_m1_kernel<<<dim3(512, 6), 256, 0, stream>>>(m1w, wb_m1c, wb_w1b);
    cvt_bf16_kernel<<<1024, 256, 0, stream>>>(m2w, wb_m2, (size_t)6 * 131072);
    bias_fold_kernel<<<dim3(2, 6), 256, 0, stream>>>(m1w, m1b, mb, bfold);
    for (int ai = 0; ai < 6; ++ai)   // Wc = W1b @ Wm (perm cols) -> m1c cols 256+
        conv_mfma(stream, wb_w1b + (size_t)ai * 131072,
                  wb_wmT + (size_t)ai * 65536, 256, nullptr, 256, 256,
                  nullptr, nullptr, nullptr,
                  wb_m1c + (size_t)ai * 262144 + 256, nullptr,
                  OM_BF16N, 512, 512, 256, 1);

    tcvt_kernel<<<dim3(NQ / 64, 4, BATCH), 256, 0, stream>>>(in_q,  TXa, 256, NQ, NT, 0);
    tcvt_kernel<<<dim3(N3C / 64, 4, BATCH), 256, 0, stream>>>(in_d3, TXa, 256, N3C, NT, NQ);
    tcvt_kernel<<<dim3(N1 / 64, 4, BATCH), 256, 0, stream>>>(in_d2, TD2, 256, N1, N1, 0);

    hipMemcpyAsync(P_Q,  in_q,  SZ_Q  * sizeof(float), hipMemcpyDeviceToDevice, stream);
    hipMemcpyAsync(P_D3, in_d3, SZ_D3 * sizeof(float), hipMemcpyDeviceToDevice, stream);

    unsigned short *TX = TXa, *TXn = TXb;

    int gi = 0, ai = 0;
    for (int L = 0; L < 9; ++L) {
        int kind = L % 3;
        if (kind == 0) {
            conv_mfma(stream, wb_gat + (size_t)gi * 65536,
                      TX + (size_t)NQ * 256, 256, nullptr, 256, NT,
                      nullptr, nullptr, nullptr, Wh3T, nullptr,
                      OM_BF16T, 256, 256, N3C, BATCH);
            conv_mfma(stream, wb_gat + (size_t)gi * 65536,
                      TD2, 256, nullptr, 256, N1,
                      nullptr, nullptr, nullptr, Wh2T, nullptr,
                      OM_BF16T, 256, 256, N1, BATCH);
            gat_fuse_kernel<<<dim3(N3C / 16, BATCH), 256, 0, stream>>>(
                Wh3T, Wh2T, gat_a + (size_t)gi * 512, P_D3, TX, N3C, N1);
            gi++;
        } else {
            int cross = (kind == 2) ? 1 : 0;
            const unsigned short* wqkv = wb_pw + (size_t)ai * 3 * 65536;  // [768][256]
            const float* pbqkv_ai = pbqkv + (size_t)ai * 768;
            const unsigned short* wm1c = wb_m1c + (size_t)ai * 262144;
            const float* bfi = bfold + (size_t)ai * 512;
            const unsigned short* wm2 = wb_m2 + (size_t)ai * 131072;
            const float* m2bi = m2b + (size_t)ai * 256;
            const int cntA = cross ? 8 : 16;
            const int cntB = cross ? 16 : 8;

            conv_mfma(stream, wqkv, TX, 256, nullptr, 256, NT, pbqkv_ai,
                      nullptr, nullptr, Qe, KVcm, OM_QKV, 768, 256, NT, BATCH);
            kv_partial_mfma<<<dim3(24, 4, BATCH), 64, 0, stream>>>(KVcm, kvp, cross);
            kv_reduce_t<<<dim3(16, 2, 32), 256, 0, stream>>>(kvp, KVq, ksb, cntA, cntB);
            attn_apply_mfma<<<dim3(NT / 64, 4, BATCH), 64, 0, stream>>>(Qe, KVq, ksb, AttT);
            conv_mfma(stream, wm1c, TX, 256, AttT, 512, NT, bfi,
                      nullptr, nullptr, HbT, nullptr, OM_BF16T, 512, 512, NT, BATCH);
            in_stats1<<<dim3(96, BATCH), 256, 0, stream>>>(HbT, part);
            in_stats2<<<dim3(BATCH, 2), 512, 0, stream>>>(part, mr);
            in_apply<<<dim3(96, BATCH), 256, 0, stream>>>(HbT, mr);
            conv_mfma(stream, wm2, HbT, 512, nullptr, 512, NT, m2bi,
                      P_Q, P_D3, TXn, nullptr, OM_ACC2_T, 256, 256, NT, BATCH);
            unsigned short* t = TX; TX = TXn; TXn = t;
            ai++;
        }
    }
    (void)in_sizes; (void)n_in; (void)out_size; (void)ws_size;
}

// Round 14
// 2053.160 us; speedup vs baseline: 1.4902x; 1.0069x over previous
//
#include <hip/hip_runtime.h>
#include <cstddef>
#include <cstdint>

// ---------------------------------------------------------------------------
// AttentionalGNN: 3 x (GAT, self-attn, cross-attn)
// B=8, D=256, NQ=4096, N3=2048, N1=16384, heads=4, dim=64
// Round 14: round-13 + bijective XCD-aware block swizzle in conv (each XCD
//   gets a contiguous chunk, o-fastest decode -> B-tile shared by 6
//   consecutive same-XCD blocks; per-XCD TX slice ~3MB fits 4MB L2).
// ---------------------------------------------------------------------------

#define NQ 4096
#define N3C 2048
#define NT 6144
#define N1 16384
#define BATCH 8

typedef __attribute__((ext_vector_type(8))) short bf16x8;
typedef __attribute__((ext_vector_type(4))) float f32x4;

__device__ __forceinline__ unsigned short f2bf(float f) {
    union { float f; unsigned u; } v; v.f = f;
    unsigned r = v.u + 0x7fffu + ((v.u >> 16) & 1u);
    return (unsigned short)(r >> 16);
}
__device__ __forceinline__ float bf2f(unsigned short h) {
    union { unsigned u; float f; } v; v.u = ((unsigned)h) << 16; return v.f;
}
__device__ __forceinline__ unsigned pack2(float lo, float hi) {
    return ((unsigned)f2bf(hi) << 16) | f2bf(lo);
}
// XOR swizzle for 64-bf16-wide (128B) LDS rows (attention tiles)
__device__ __forceinline__ int swz(int row, int byteoff) {
    return row * 128 + (byteoff ^ ((row & 7) << 4));
}

__device__ __forceinline__ void gload_lds16(const void* g, void* l) {
    __builtin_amdgcn_global_load_lds(
        (const __attribute__((address_space(1))) unsigned int*)g,
        (__attribute__((address_space(3))) unsigned int*)l, 16, 0, 0);
}

#define OM_BF16T  1
#define OM_BF16N  3
#define OM_ACC2_T 6
#define OM_QKV    7

// ---------------------------------------------------------------------------
// MFMA GEMM: out(o,n) = bias[o] + sum_c W[o][c] * X[n][c]   (per batch b)
// BK=32, double-buffered LDS, one barrier/iter.  XCD-aware block remap:
// flatten id, chunk per XCD (nwg%8==0 for all our grids), o-fastest decode.
// ---------------------------------------------------------------------------
__global__ __launch_bounds__(256) void conv_mfma_kernel(
    const unsigned short* __restrict__ W,
    const unsigned short* __restrict__ XA, int CA,
    const unsigned short* __restrict__ XB,
    int C, int xstride,
    const float* __restrict__ bias,
    float* __restrict__ outF, float* __restrict__ outF2,
    unsigned short* __restrict__ outT,
    unsigned short* __restrict__ outT2,
    int outMode, int O, int ldo, int N)
{
    // ---- XCD-aware bijective remap (o-fastest within contiguous chunks) ---
    const int nx = gridDim.x, ny = gridDim.y;
    int wgl = blockIdx.x + nx * (blockIdx.y + ny * blockIdx.z);
    const int nwg = nx * ny * (int)gridDim.z;
    int id;
    if ((nwg & 7) == 0) {
        const int chunk = nwg >> 3;
        id = (wgl & 7) * chunk + (wgl >> 3);
    } else {
        id = wgl;
    }
    const int o0 = (id % ny) * 128;
    int rest = id / ny;
    const int n0 = (rest % nx) * 128;
    const int b  = rest / nx;

    const int tid = threadIdx.x;
    const int wid = tid >> 6, lane = tid & 63;
    const int wr = wid >> 1, wc = wid & 1;
    const int lr = lane & 15, kg = lane >> 4;
    const int CB = C - CA;

    __shared__ short As[2][128 * 32];   // 8 KB each
    __shared__ short Bs[2][128 * 32];

    auto stage = [&](int buf, int c0) {
        #pragma unroll
        for (int it = 0; it < 2; ++it) {
            int chunk = it * 256 + tid;
            int row = chunk >> 2;
            int ksw = (chunk & 3) ^ (row & 3);
            gload_lds16(W + (size_t)(o0 + row) * C + c0 + ksw * 8,
                        (char*)As[buf] + it * 4096 + wid * 1024);
        }
        #pragma unroll
        for (int it = 0; it < 2; ++it) {
            int chunk = it * 256 + tid;
            int row = chunk >> 2;
            int ksw = (chunk & 3) ^ (row & 3);
            int cc = c0 + ksw * 8;
            const unsigned short* src =
                (cc < CA) ? XA + ((size_t)b * xstride + n0 + row) * CA + cc
                          : XB + ((size_t)b * xstride + n0 + row) * CB + (cc - CA);
            gload_lds16(src, (char*)Bs[buf] + it * 4096 + wid * 1024);
        }
    };

    f32x4 acc[4][4] = {};

    stage(0, 0);
    __syncthreads();              // drain prologue loads

    int cur = 0;
    for (int c0 = 0; c0 < C; c0 += 32) {
        if (c0 + 32 < C) stage(cur ^ 1, c0 + 32);   // issue next-tile loads FIRST

        bf16x8 af[4], bfr[4];
        #pragma unroll
        for (int m = 0; m < 4; ++m) {
            int row = wr * 64 + m * 16 + lr;
            af[m] = *(const bf16x8*)((const char*)As[cur] + row * 64 + ((kg ^ (row & 3)) * 16));
        }
        #pragma unroll
        for (int n = 0; n < 4; ++n) {
            int row = wc * 64 + n * 16 + lr;
            bfr[n] = *(const bf16x8*)((const char*)Bs[cur] + row * 64 + ((kg ^ (row & 3)) * 16));
        }
        #pragma unroll
        for (int m = 0; m < 4; ++m)
            #pragma unroll
            for (int n = 0; n < 4; ++n)
                acc[m][n] = __builtin_amdgcn_mfma_f32_16x16x32_bf16(
                    af[m], bfr[n], acc[m][n], 0, 0, 0);

        __syncthreads();          // one barrier/iter: drains next-tile loads
        cur ^= 1;
    }

    // C/D frag: col = lane&15, row = (lane>>4)*4 + r
    #pragma unroll
    for (int m = 0; m < 4; ++m) {
        const int ob = o0 + wr * 64 + m * 16 + (lane >> 4) * 4;
        float bv[4] = {0.f, 0.f, 0.f, 0.f};
        if (bias) {
            #pragma unroll
            for (int r = 0; r < 4; ++r) bv[r] = bias[ob + r];
        }
        #pragma unroll
        for (int n = 0; n < 4; ++n) {
            const int col = n0 + wc * 64 + n * 16 + lr;
            f32x4 v = acc[m][n];
            #pragma unroll
            for (int r = 0; r < 4; ++r) v[r] += bv[r];
            if (outMode == OM_BF16T) {
                *(uint2*)(outT + ((size_t)b * N + col) * ldo + ob) =
                    make_uint2(pack2(v[0], v[1]), pack2(v[2], v[3]));
            } else if (outMode == OM_QKV) {
                if (ob < 256) {
                    #pragma unroll
                    for (int r = 0; r < 4; ++r) {
                        float x = v[r];
                        v[r] = x > 0.f ? x + 1.0f : __expf(x);
                    }
                    *(uint2*)(outT + ((size_t)b * N + col) * 256 + ob) =
                        make_uint2(pack2(v[0], v[1]), pack2(v[2], v[3]));
                } else {
                    #pragma unroll
                    for (int r = 0; r < 4; ++r) {
                        int ch = ob + r - 256;
                        float x = v[r];
                        if (ch < 256) x = x > 0.f ? x + 1.0f : __expf(x);
                        outT2[((size_t)b * 512 + ch) * N + col] = f2bf(x);
                    }
                }
            } else if (outMode == OM_ACC2_T) {
                #pragma unroll
                for (int r = 0; r < 4; ++r) {
                    float* p;
                    if (col < NQ)
                        p = outF  + ((size_t)b * 256 + ob + r) * NQ  + col;
                    else
                        p = outF2 + ((size_t)b * 256 + ob + r) * N3C + (col - NQ);
                    float nv = *p + v[r];
                    *p = nv;
                    v[r] = nv;
                }
                *(uint2*)(outT + ((size_t)b * N + col) * ldo + ob) =
                    make_uint2(pack2(v[0], v[1]), pack2(v[2], v[3]));
            } else {  // OM_BF16N (weight-build, b==0)
                #pragma unroll
                for (int r = 0; r < 4; ++r)
                    outT[(size_t)(ob + r) * ldo + col] = f2bf(v[r]);
            }
        }
    }
}

// ---------------------------------------------------------------------------
// fp32 [B][C][Ncols] -> bf16 [B][rs][C] at row offset ro
// ---------------------------------------------------------------------------
__global__ __launch_bounds__(256) void tcvt_kernel(
    const float* __restrict__ in, unsigned short* __restrict__ out,
    int C, int Ncols, int rs, int ro)
{
    int b = blockIdx.z;
    int n0 = blockIdx.x * 64, c0 = blockIdx.y * 64;
    __shared__ float t[64][65];
    int a = threadIdx.x & 63, q = threadIdx.x >> 6;
    for (int i = q; i < 64; i += 4)
        t[i][a] = in[((size_t)b * C + c0 + i) * Ncols + n0 + a];
    __syncthreads();
    for (int i = q; i < 64; i += 4)
        out[((size_t)b * rs + ro + n0 + i) * C + c0 + a] = f2bf(t[a][i]);
}

__global__ __launch_bounds__(256) void cvt_bf16_kernel(
    const float* __restrict__ in, unsigned short* __restrict__ out, size_t n)
{
    size_t i = (size_t)blockIdx.x * 256 + threadIdx.x;
    size_t stride = (size_t)gridDim.x * 256;
    for (; i < n; i += stride) out[i] = f2bf(in[i]);
}

// pw [18][256][256] -> bf16, ALL sections row-permuted h-major:
// out_row r <- src_row (r&63)*4 + (r>>6)
__global__ __launch_bounds__(256) void pwperm_cvt_kernel(
    const float* __restrict__ pw, unsigned short* __restrict__ out)
{
    size_t i = (size_t)blockIdx.x * 256 + threadIdx.x;
    size_t stride = (size_t)gridDim.x * 256;
    size_t total = (size_t)18 * 65536;
    for (; i < total; i += stride) {
        int sec = (int)(i >> 16);
        int r = (int)((i >> 8) & 255);
        int c = (int)(i & 255);
        int srow = (r & 63) * 4 + (r >> 6);
        out[i] = f2bf(pw[(size_t)sec * 65536 + (size_t)srow * 256 + c]);
    }
}

// permuted qkv bias (768/ai): all three sections h-major permuted
__global__ __launch_bounds__(256) void pbqkv_perm_kernel(
    const float* __restrict__ pb, float* __restrict__ pbqkv)
{
    int ai = blockIdx.x, sec = blockIdx.y, r = threadIdx.x;
    pbqkv[ai * 768 + sec * 256 + r] =
        pb[ai * 768 + sec * 256 + (r & 63) * 4 + (r >> 6)];
}

// fp32 [Z][D][D] -> bf16 transposed [Z][D][D]
__global__ __launch_bounds__(256) void wtrans_cvt_kernel(
    const float* __restrict__ in, unsigned short* __restrict__ out, int D)
{
    int z = blockIdx.z;
    int i0 = blockIdx.x * 64, j0 = blockIdx.y * 64;
    __shared__ float t[64][65];
    int a = threadIdx.x & 63, q = threadIdx.x >> 6;
    const float* src = in + (size_t)z * D * D;
    unsigned short* dst = out + (size_t)z * D * D;
    for (int i = q; i < 64; i += 4)
        t[i][a] = src[(size_t)(j0 + i) * D + i0 + a];
    __syncthreads();
    for (int i = q; i < 64; i += 4)
        dst[(size_t)(i0 + i) * D + j0 + a] = f2bf(t[a][i]);
}

// wmT with h-major permutation: out[ai][n'][c] = mw[ai][c][(n'&63)*4+(n'>>6)]
__global__ __launch_bounds__(256) void wmt_perm_kernel(
    const float* __restrict__ mw, unsigned short* __restrict__ out)
{
    int ai = blockIdx.y, np = blockIdx.x, c = threadIdx.x;
    int orig = (np & 63) * 4 + (np >> 6);
    out[(size_t)ai * 65536 + (size_t)np * 256 + c] =
        f2bf(mw[(size_t)ai * 65536 + (size_t)c * 256 + orig]);
}

// split m1w: A-half into combined [512][512] cols 0-255; B-half [512][256]
__global__ __launch_bounds__(256) void ext_m1_kernel(
    const float* __restrict__ m1w, unsigned short* __restrict__ m1c,
    unsigned short* __restrict__ w1b)
{
    int ai = blockIdx.y, o = blockIdx.x, c = threadIdx.x;
    const float* src = m1w + (size_t)ai * 262144 + (size_t)o * 512;
    m1c[(size_t)ai * 262144 + (size_t)o * 512 + c] = f2bf(src[c]);
    w1b[(size_t)ai * 131072 + (size_t)o * 256 + c] = f2bf(src[256 + c]);
}

// bfold[ai][o] = m1b[ai][o] + sum_c m1w[ai][o][256+c] * mb[ai][c]
__global__ __launch_bounds__(256) void bias_fold_kernel(
    const float* __restrict__ m1w, const float* __restrict__ m1b,
    const float* __restrict__ mb, float* __restrict__ bf)
{
    int ai = blockIdx.y;
    int o = blockIdx.x * 256 + threadIdx.x;
    const float* wrow = m1w + (size_t)ai * 262144 + (size_t)o * 512 + 256;
    const float* mbp = mb + (size_t)ai * 256;
    float s = m1b[(size_t)ai * 512 + o];
    for (int c = 0; c < 256; ++c) s += wrow[c] * mbp[c];
    bf[(size_t)ai * 512 + o] = s;
}

// ---------------------------------------------------------------------------
// Instance norm on bf16 [B][NT][512], per-segment (rows<4096 seg0, else seg1).
// 64-row chunks: grid (96, B) for stats1/apply -> 768 blocks.
// ---------------------------------------------------------------------------
__global__ __launch_bounds__(256) void in_stats1(
    const unsigned short* __restrict__ x, float* __restrict__ part)
{
    int b = blockIdx.y, ch = blockIdx.x, tid = threadIdx.x;
    float s0 = 0, q0 = 0, s1 = 0, q1 = 0;
    for (int r = 0; r < 64; ++r) {
        size_t base = ((size_t)b * NT + ch * 64 + r) * 512;
        float v0 = bf2f(x[base + tid]);
        float v1 = bf2f(x[base + 256 + tid]);
        s0 += v0; q0 += v0 * v0; s1 += v1; q1 += v1 * v1;
    }
    size_t p = ((size_t)(b * 96 + ch)) * 1024;
    part[p + tid] = s0;  part[p + 256 + tid] = q0;
    part[p + 512 + tid] = s1;  part[p + 768 + tid] = q1;
}

// grid (B, 2): per-seg reduce.  mr[b][seg][1024]
__global__ __launch_bounds__(512) void in_stats2(
    const float* __restrict__ part, float* __restrict__ mr)
{
    int b = blockIdx.x, seg = blockIdx.y, c = threadIdx.x;
    int half = c >> 8, cc = c & 255;
    int ch0 = seg ? 64 : 0, nch = seg ? 32 : 64;
    float Nf = seg ? (float)N3C : (float)NQ;
    float s = 0, q = 0;
    for (int ch = ch0; ch < ch0 + nch; ++ch) {
        size_t p = ((size_t)(b * 96 + ch)) * 1024 + half * 512;
        s += part[p + cc];
        q += part[p + 256 + cc];
    }
    float m = s / Nf;
    float var = q / Nf - m * m;
    size_t o = ((size_t)b * 2 + seg) * 1024;
    mr[o + c] = m;
    mr[o + 512 + c] = rsqrtf(var + 1e-5f);
}

__global__ __launch_bounds__(256) void in_apply(
    unsigned short* __restrict__ x, const float* __restrict__ mr)
{
    int b = blockIdx.y, ch = blockIdx.x, tid = threadIdx.x;
    int seg = (ch >= 64);
    size_t o = ((size_t)b * 2 + seg) * 1024;
    float m0 = mr[o + tid];
    float r0 = mr[o + 512 + tid];
    float m1 = mr[o + 256 + tid];
    float r1 = mr[o + 768 + tid];
    for (int r = 0; r < 64; ++r) {
        size_t base = ((size_t)b * NT + ch * 64 + r) * 512;
        float v0 = (bf2f(x[base + tid]) - m0) * r0;
        x[base + tid] = f2bf(v0 > 0.f ? v0 : 0.f);
        float v1 = (bf2f(x[base + 256 + tid]) - m1) * r1;
        x[base + 256 + tid] = f2bf(v1 > 0.f ? v1 : 0.f);
    }
}

// ---------------------------------------------------------------------------
// KV split partial (MFMA).  KVcm bf16 [B][512][NT] channel-major h-grouped:
// k channel = h*64+d (elu'd), v channel = 256+h*64+q.
// grid (24, 4, 8): sx<16 -> srcseg0 (m 0-4095), else srcseg1 (m 4096-6143).
// dstseg = cross ? 1-srcseg : srcseg.  chunk = 256 m per split (4 x 64 tiles).
// ---------------------------------------------------------------------------
__global__ __launch_bounds__(64) void kv_partial_mfma(
    const unsigned short* __restrict__ kvcm, float* __restrict__ part,
    int cross)
{
    const int sx = blockIdx.x, h = blockIdx.y, b = blockIdx.z;
    const int srcseg = sx >> 4;
    const int slot = sx & 15;
    const int Mb0 = srcseg ? NQ + slot * 256 : slot * 256;
    const int dstseg = cross ? 1 - srcseg : srcseg;
    const int l = threadIdx.x;
    const int lr = l & 15, kg = l >> 4;

    __shared__ unsigned short ke[64 * 64];
    __shared__ unsigned short ve[64 * 64];

    const size_t kbase = ((size_t)b * 512 + h * 64) * NT;
    const size_t vbase = kbase + (size_t)256 * NT;

    f32x4 acc[4][4] = {};
    float ksacc = 0.f;

    for (int t = 0; t < 4; ++t) {
        const int mb = Mb0 + t * 64;
        #pragma unroll
        for (int p = 0; p < 8; ++p) {
            int row = p * 8 + (l >> 3);
            bf16x8 k8 = *(const bf16x8*)(kvcm + kbase + (size_t)row * NT + mb + (l & 7) * 8);
            bf16x8 v8 = *(const bf16x8*)(kvcm + vbase + (size_t)row * NT + mb + (l & 7) * 8);
            *(bf16x8*)((char*)ke + swz(row, (l & 7) * 16)) = k8;
            *(bf16x8*)((char*)ve + swz(row, (l & 7) * 16)) = v8;
        }

        #pragma unroll
        for (int j = 0; j < 8; ++j) {
            bf16x8 kk = *(const bf16x8*)((const char*)ke + swz(l, j * 16));
            #pragma unroll
            for (int e = 0; e < 8; ++e) ksacc += bf2f((unsigned short)kk[e]);
        }

        #pragma unroll
        for (int ks = 0; ks < 2; ++ks) {
            bf16x8 af[4], bfr[4];
            #pragma unroll
            for (int di = 0; di < 4; ++di)
                af[di] = *(const bf16x8*)((const char*)ke + swz(di * 16 + lr, ks * 64 + kg * 16));
            #pragma unroll
            for (int qi = 0; qi < 4; ++qi)
                bfr[qi] = *(const bf16x8*)((const char*)ve + swz(qi * 16 + lr, ks * 64 + kg * 16));
            #pragma unroll
            for (int di = 0; di < 4; ++di)
                #pragma unroll
                for (int qi = 0; qi < 4; ++qi)
                    acc[di][qi] = __builtin_amdgcn_mfma_f32_16x16x32_bf16(
                        af[di], bfr[qi], acc[di][qi], 0, 0, 0);
        }
    }

    float* pb_ = part + ((size_t)((b * 4 + h) * 2 + dstseg) * 16 + slot) * 4160;
    #pragma unroll
    for (int di = 0; di < 4; ++di)
        #pragma unroll
        for (int qi = 0; qi < 4; ++qi)
            #pragma unroll
            for (int r = 0; r < 4; ++r)
                pb_[(di * 16 + kg * 4 + r) * 64 + qi * 16 + lr] = acc[di][qi][r];
    pb_[4096 + l] = ksacc;
}

// reduce partials -> KVq bf16 [bh][seg][q*64+d] (transposed) + ksum fp32.
// grid (16, 2, 32)
__global__ __launch_bounds__(256) void kv_reduce_t(
    const float* __restrict__ part, unsigned short* __restrict__ KVq,
    float* __restrict__ ks, int cntA, int cntB)
{
    const int seg = blockIdx.y, bh = blockIdx.z;
    const int cnt = seg ? cntB : cntA;
    const float* p0 = part + ((size_t)(bh * 2 + seg) * 16) * 4160;
    int idx = blockIdx.x * 256 + threadIdx.x;
    int q = idx >> 6, d = idx & 63;
    float t = 0.f;
    for (int s = 0; s < cnt; ++s) t += p0[(size_t)s * 4160 + d * 64 + q];
    KVq[((size_t)(bh * 2 + seg)) * 4096 + idx] = f2bf(t);
    if (blockIdx.x == 0 && threadIdx.x < 64) {
        float t2 = 0.f;
        for (int s = 0; s < cnt; ++s) t2 += p0[(size_t)s * 4160 + 4096 + threadIdx.x];
        ks[(bh * 2 + seg) * 64 + threadIdx.x] = t2;
    }
}

// ---------------------------------------------------------------------------
// apply (MFMA): qe bf16 [B][NT][256] h-major, KVq [bh][seg][q][d], ks fp32.
// grid (96, 4, 8): seg from m0.
// ---------------------------------------------------------------------------
__global__ __launch_bounds__(64) void attn_apply_mfma(
    const unsigned short* __restrict__ qe,
    const unsigned short* __restrict__ KVq,
    const float* __restrict__ ksum,
    unsigned short* __restrict__ outT)
{
    const int h = blockIdx.y, b = blockIdx.z;
    const int m0 = blockIdx.x * 64;
    const int seg = (m0 >= NQ);
    const int bhs = (b * 4 + h) * 2 + seg;
    const int l = threadIdx.x;
    const int lr = l & 15, kg = l >> 4;

    __shared__ unsigned short kv[64 * 64];
    __shared__ float zl[64];
    __shared__ float kss[64];

    #pragma unroll
    for (int i = 0; i < 8; ++i) {
        int q = i * 8 + (l >> 3);
        bf16x8 v8 = *(const bf16x8*)(KVq + (size_t)bhs * 4096 + q * 64 + (l & 7) * 8);
        *(bf16x8*)((char*)kv + swz(q, (l & 7) * 16)) = v8;
    }
    kss[l] = ksum[bhs * 64 + l];

    const unsigned short* qrow = qe + ((size_t)b * NT + m0 + l) * 256 + h * 64;
    float den = 0.f;
    #pragma unroll
    for (int i = 0; i < 8; ++i) {
        bf16x8 q8 = *(const bf16x8*)(qrow + i * 8);
        #pragma unroll
        for (int j = 0; j < 8; ++j) den += bf2f((unsigned short)q8[j]) * kss[i * 8 + j];
    }
    zl[l] = 1.0f / (den + 1e-6f);

    f32x4 acc[4][4] = {};   // [qi][mi]
    #pragma unroll
    for (int ks = 0; ks < 2; ++ks) {
        bf16x8 af[4], bfr[4];
        #pragma unroll
        for (int qi = 0; qi < 4; ++qi)
            af[qi] = *(const bf16x8*)((const char*)kv + swz(qi * 16 + lr, ks * 64 + kg * 16));
        #pragma unroll
        for (int mi = 0; mi < 4; ++mi)
            bfr[mi] = *(const bf16x8*)(qe + ((size_t)b * NT + m0 + mi * 16 + lr) * 256
                                       + h * 64 + ks * 32 + kg * 8);
        #pragma unroll
        for (int qi = 0; qi < 4; ++qi)
            #pragma unroll
            for (int mi = 0; mi < 4; ++mi)
                acc[qi][mi] = __builtin_amdgcn_mfma_f32_16x16x32_bf16(
                    af[qi], bfr[mi], acc[qi][mi], 0, 0, 0);
    }

    #pragma unroll
    for (int mi = 0; mi < 4; ++mi) {
        int m = m0 + mi * 16 + lr;
        float Z = zl[mi * 16 + lr];
        unsigned short* dst = outT + ((size_t)b * NT + m) * 256 + h * 64;
        #pragma unroll
        for (int qi = 0; qi < 4; ++qi) {
            f32x4 v = acc[qi][mi];
            *(uint2*)(dst + qi * 16 + kg * 4) =
                make_uint2(pack2(v[0] * Z, v[1] * Z), pack2(v[2] * Z, v[3] * Z));
        }
    }
}

// ---------------------------------------------------------------------------
// GAT: wave-per-node; writes fp32 P_D3 and bf16 rows 4096+ of combined TX.
// ---------------------------------------------------------------------------
__global__ __launch_bounds__(256) void gat_fuse_kernel(
    const unsigned short* __restrict__ Wh3T,
    const unsigned short* __restrict__ Wh2T,
    const float* __restrict__ avec,
    float* __restrict__ d3out, unsigned short* __restrict__ tx,
    int n3, int n1)
{
    const int b = blockIdx.y;
    const int n0 = blockIdx.x * 16;
    const int wv = threadIdx.x >> 6, lane = threadIdx.x & 63;
    __shared__ float hbuf[16][256];

    float a1[4], a2[4];
    #pragma unroll
    for (int r = 0; r < 4; ++r) {
        a1[r] = avec[lane + 64 * r];
        a2[r] = avec[256 + lane + 64 * r];
    }

    for (int i = 0; i < 4; ++i) {
        int nl = wv * 4 + i;
        int n = n0 + nl;
        float rows[9][4];
        const unsigned short* p3 = Wh3T + ((size_t)b * n3 + n) * 256;
        #pragma unroll
        for (int r = 0; r < 4; ++r) rows[0][r] = bf2f(p3[lane + 64 * r]);
        #pragma unroll
        for (int l2 = 1; l2 < 9; ++l2) {
            const unsigned short* p2 = Wh2T + ((size_t)b * n1 + (size_t)n * 8 + (l2 - 1)) * 256;
            #pragma unroll
            for (int r = 0; r < 4; ++r) rows[l2][r] = bf2f(p2[lane + 64 * r]);
        }

        float part[10];
        {
            float s = 0.f;
            #pragma unroll
            for (int r = 0; r < 4; ++r) s += rows[0][r] * a1[r];
            part[0] = s;
        }
        #pragma unroll
        for (int l2 = 0; l2 < 9; ++l2) {
            float s = 0.f;
            #pragma unroll
            for (int r = 0; r < 4; ++r) s += rows[l2][r] * a2[r];
            part[1 + l2] = s;
        }
        #pragma unroll
        for (int msk = 1; msk < 64; msk <<= 1)
            #pragma unroll
            for (int j = 0; j < 10; ++j)
                part[j] += __shfl_xor(part[j], msk, 64);

        float s3 = part[0];
        float e[9], mx = -1e30f;
        #pragma unroll
        for (int l2 = 0; l2 < 9; ++l2) {
            float t = s3 + part[1 + l2];
            t = t > 0.f ? t : 0.2f * t;
            e[l2] = t; mx = fmaxf(mx, t);
        }
        float sum = 0.f;
        #pragma unroll
        for (int l2 = 0; l2 < 9; ++l2) { e[l2] = __expf(e[l2] - mx); sum += e[l2]; }
        float inv = 1.0f / sum;
        #pragma unroll
        for (int r = 0; r < 4; ++r) {
            float t = 0.f;
            #pragma unroll
            for (int l2 = 0; l2 < 9; ++l2) t += e[l2] * rows[l2][r];
            t *= inv;
            t = t > 0.f ? t : __expf(t) - 1.0f;  // elu
            hbuf[nl][lane + 64 * r] = t;
            tx[((size_t)b * NT + NQ + n) * 256 + lane + 64 * r] = f2bf(t);
        }
    }
    __syncthreads();
    const int c = threadIdx.x;
    float* dst = d3out + ((size_t)b * 256 + c) * n3 + n0;
    #pragma unroll
    for (int g = 0; g < 4; ++g) {
        f32x4 v;
        #pragma unroll
        for (int k = 0; k < 4; ++k) v[k] = hbuf[g * 4 + k][c];
        *(f32x4*)(dst + g * 4) = v;
    }
}

// ---------------------------------------------------------------------------
// host side
// ---------------------------------------------------------------------------
static void conv_mfma(hipStream_t s, const unsigned short* W,
                      const unsigned short* XA, int CA,
                      const unsigned short* XB, int C, int xstride,
                      const float* bias, float* outF, float* outF2,
                      unsigned short* outT, unsigned short* outT2,
                      int mode, int O, int ldo, int N, int nb)
{
    dim3 g(N / 128, O / 128, nb);
    conv_mfma_kernel<<<g, 256, 0, s>>>(W, XA, CA, XB, C, xstride, bias,
                                       outF, outF2, outT, outT2, mode, O, ldo, N);
}

extern "C" void kernel_launch(void* const* d_in, const int* in_sizes, int n_in,
                              void* d_out, int out_size, void* d_ws, size_t ws_size,
                              hipStream_t stream)
{
    const float* in_q  = (const float*)d_in[0];
    const float* in_d3 = (const float*)d_in[1];
    const float* in_d2 = (const float*)d_in[2];
    const float* gat_W = (const float*)d_in[3];
    const float* gat_a = (const float*)d_in[4];
    const float* pw    = (const float*)d_in[5];
    const float* pb    = (const float*)d_in[6];
    const float* mw    = (const float*)d_in[7];
    const float* mb    = (const float*)d_in[8];
    const float* m1w   = (const float*)d_in[9];
    const float* m1b   = (const float*)d_in[10];
    const float* m2w   = (const float*)d_in[11];
    const float* m2b   = (const float*)d_in[12];

    const size_t SZ_Q  = (size_t)BATCH * 256 * NQ;
    const size_t SZ_D3 = (size_t)BATCH * 256 * N3C;
    const size_t SZ_T  = (size_t)BATCH * NT * 256;    // combined bf16 elems

    float* P_Q  = (float*)d_out;
    float* P_D3 = P_Q + SZ_Q;

    float* w = (float*)d_ws;
    size_t off = 0;
    unsigned short* Qe   = (unsigned short*)(w + off); off += SZ_T / 2;      // 25 MB
    unsigned short* KVcm = (unsigned short*)(w + off); off += SZ_T;          // 50 MB [B][512][NT]
    unsigned short* AttT = (unsigned short*)(w + off); off += SZ_T / 2;
    unsigned short* HbT  = (unsigned short*)(w + off); off += SZ_T;          // [B][NT][512]
    float* kvp = w + off; off += (size_t)32 * 2 * 16 * 4160;                 // 17 MB
    unsigned short* KVq = (unsigned short*)(w + off); off += (size_t)64 * 4096 / 2;
    float* ksb = w + off; off += 64 * 64;
    float* part = w + off; off += (size_t)BATCH * 96 * 1024;
    float* mr   = w + off; off += (size_t)BATCH * 2 * 1024;
    unsigned short* TXa = (unsigned short*)(w + off); off += SZ_T / 2;
    unsigned short* TXb = (unsigned short*)(w + off); off += SZ_T / 2;
    unsigned short* TD2 = (unsigned short*)(w + off); off += (size_t)BATCH * N1 * 256 / 2;
    unsigned short* wb_pw  = (unsigned short*)(w + off); off += (size_t)18 * 65536 / 2;
    unsigned short* wb_gat = (unsigned short*)(w + off); off += (size_t)3 * 65536 / 2;
    unsigned short* wb_wmT = (unsigned short*)(w + off); off += (size_t)6 * 65536 / 2;
    unsigned short* wb_m1c = (unsigned short*)(w + off); off += (size_t)6 * 262144 / 2;
    unsigned short* wb_w1b = (unsigned short*)(w + off); off += (size_t)6 * 131072 / 2;
    unsigned short* wb_m2  = (unsigned short*)(w + off); off += (size_t)6 * 131072 / 2;
    float* bfold = w + off; off += 6 * 512;
    float* pbqkv = w + off; off += 6 * 768;

    // GAT overlays: Wh2T (67 MB) spans Qe+KVcm (75 MB); Wh3T (8.4 MB) in AttT.
    unsigned short* Wh2T = Qe;
    unsigned short* Wh3T = AttT;

    // ---- setup ----
    pwperm_cvt_kernel<<<1024, 256, 0, stream>>>(pw, wb_pw);
    pbqkv_perm_kernel<<<dim3(6, 3), 256, 0, stream>>>(pb, pbqkv);
    wtrans_cvt_kernel<<<dim3(4, 4, 3), 256, 0, stream>>>(gat_W, wb_gat, 256);
    wmt_perm_kernel<<<dim3(256, 6), 256, 0, stream>>>(mw, wb_wmT);
    ext_m1_kernel<<<dim3(512, 6), 256, 0, stream>>>(m1w, wb_m1c, wb_w1b);
    cvt_bf16_kernel<<<1024, 256, 0, stream>>>(m2w, wb_m2, (size_t)6 * 131072);
    bias_fold_kernel<<<dim3(2, 6), 256, 0, stream>>>(m1w, m1b, mb, bfold);
    for (int ai = 0; ai < 6; ++ai)   // Wc = W1b @ Wm (perm cols) -> m1c cols 256+
        conv_mfma(stream, wb_w1b + (size_t)ai * 131072,
                  wb_wmT + (size_t)ai * 65536, 256, nullptr, 256, 256,
                  nullptr, nullptr, nullptr,
                  wb_m1c + (size_t)ai * 262144 + 256, nullptr,
                  OM_BF16N, 512, 512, 256, 1);

    tcvt_kernel<<<dim3(NQ / 64, 4, BATCH), 256, 0, stream>>>(in_q,  TXa, 256, NQ, NT, 0);
    tcvt_kernel<<<dim3(N3C / 64, 4, BATCH), 256, 0, stream>>>(in_d3, TXa, 256, N3C, NT, NQ);
    tcvt_kernel<<<dim3(N1 / 64, 4, BATCH), 256, 0, stream>>>(in_d2, TD2, 256, N1, N1, 0);

    hipMemcpyAsync(P_Q,  in_q,  SZ_Q  * sizeof(float), hipMemcpyDeviceToDevice, stream);
    hipMemcpyAsync(P_D3, in_d3, SZ_D3 * sizeof(float), hipMemcpyDeviceToDevice, stream);

    unsigned short *TX = TXa, *TXn = TXb;

    int gi = 0, ai = 0;
    for (int L = 0; L < 9; ++L) {
        int kind = L % 3;
        if (kind == 0) {
            conv_mfma(stream, wb_gat + (size_t)gi * 65536,
                      TX + (size_t)NQ * 256, 256, nullptr, 256, NT,
                      nullptr, nullptr, nullptr, Wh3T, nullptr,
                      OM_BF16T, 256, 256, N3C, BATCH);
            conv_mfma(stream, wb_gat + (size_t)gi * 65536,
                      TD2, 256, nullptr, 256, N1,
                      nullptr, nullptr, nullptr, Wh2T, nullptr,
                      OM_BF16T, 256, 256, N1, BATCH);
            gat_fuse_kernel<<<dim3(N3C / 16, BATCH), 256, 0, stream>>>(
                Wh3T, Wh2T, gat_a + (size_t)gi * 512, P_D3, TX, N3C, N1);
            gi++;
        } else {
            int cross = (kind == 2) ? 1 : 0;
            const unsigned short* wqkv = wb_pw + (size_t)ai * 3 * 65536;  // [768][256]
            const float* pbqkv_ai = pbqkv + (size_t)ai * 768;
            const unsigned short* wm1c = wb_m1c + (size_t)ai * 262144;
            const float* bfi = bfold + (size_t)ai * 512;
            const unsigned short* wm2 = wb_m2 + (size_t)ai * 131072;
            const float* m2bi = m2b + (size_t)ai * 256;
            const int cntA = cross ? 8 : 16;
            const int cntB = cross ? 16 : 8;

            conv_mfma(stream, wqkv, TX, 256, nullptr, 256, NT, pbqkv_ai,
                      nullptr, nullptr, Qe, KVcm, OM_QKV, 768, 256, NT, BATCH);
            kv_partial_mfma<<<dim3(24, 4, BATCH), 64, 0, stream>>>(KVcm, kvp, cross);
            kv_reduce_t<<<dim3(16, 2, 32), 256, 0, stream>>>(kvp, KVq, ksb, cntA, cntB);
            attn_apply_mfma<<<dim3(NT / 64, 4, BATCH), 64, 0, stream>>>(Qe, KVq, ksb, AttT);
            conv_mfma(stream, wm1c, TX, 256, AttT, 512, NT, bfi,
                      nullptr, nullptr, HbT, nullptr, OM_BF16T, 512, 512, NT, BATCH);
            in_stats1<<<dim3(96, BATCH), 256, 0, stream>>>(HbT, part);
            in_stats2<<<dim3(BATCH, 2), 512, 0, stream>>>(part, mr);
            in_apply<<<dim3(96, BATCH), 256, 0, stream>>>(HbT, mr);
            conv_mfma(stream, wm2, HbT, 512, nullptr, 512, NT, m2bi,
                      P_Q, P_D3, TXn, nullptr, OM_ACC2_T, 256, 256, NT, BATCH);
            unsigned short* t = TX; TX = TXn; TXn = t;
            ai++;
        }
    }
    (void)in_sizes; (void)n_in; (void)out_size; (void)ws_size;
}